// Round 11
// baseline (172.562 us; speedup 1.0000x reference)
//
#include <hip/hip_runtime.h>
#include <hip/hip_bf16.h>
#include <stdint.h>

#define B_      4
#define CIN     512
#define COUT    512
#define L_      4096
#define K_      7
#define OUT_LEN 4090

typedef unsigned short ushort_t;
typedef __attribute__((ext_vector_type(8))) __bf16 bf16x8;
typedef __attribute__((ext_vector_type(4))) float f32x4;

__device__ __forceinline__ uint32_t f2bf(float f) {
    uint32_t u = __float_as_uint(f);
    return (u + 0x7fffu + ((u >> 16) & 1u)) >> 16;
}

__device__ __forceinline__ uint32_t pack2bf(float s0, float s1) {   // s0 -> low 16
    __hip_bfloat162 h = __float22bfloat162_rn(make_float2(s0, s1));
    uint32_t r;
    __builtin_memcpy(&r, &h, 4);
    return r;
}

__device__ __forceinline__ uint32_t interp1(uint32_t wl, uint32_t wh, float g0, float g1) {
    const float l0 = __uint_as_float(wl << 16);
    const float l1 = __uint_as_float(wl & 0xffff0000u);
    const float h0 = __uint_as_float(wh << 16);
    const float h1 = __uint_as_float(wh & 0xffff0000u);
    return pack2bf(g0 * l0 + g1 * h0, g0 * l1 + g1 * h1);
}

__device__ __forceinline__ void async16(const void* g, void* l) {
    __builtin_amdgcn_global_load_lds(
        (const __attribute__((address_space(1))) unsigned int*)g,
        (__attribute__((address_space(3))) unsigned int*)l, 16, 0, 0);
}

// =====================================================================================
//  NEW PATH
//  Layouts (step s = cc*7 + k, s = 0..111):
//   Wr: slab s -> 512 d-rows x 32 bf16 (channels cc*32..+31), 64 B/row,
//       16B-chunk c stored at physical chunk c ^ ((d>>1)&3)      [pre-swizzled]
//   P : slab (s, b, obx) -> 128 o-rows x 32 bf16, 64 B/row,
//       chunk c stored at physical chunk c ^ ((o_loc>>1)&3)      [pre-swizzled]
//  gemm (round 10): m201-style PHASE SANDWICH on r7's geometry.  512 thr / 8 waves,
//  256d x 128o tile, 4-slab K=32 rotation (r7's verified addressing).  Per slab,
//  2 phases: {ds_read subtile; issue stage(s+3); s_barrier; lgkmcnt(0); setprio;
//  8 MFMA; setprio(0)} x2, then slab-end counted vmcnt(6) + s_barrier (never
//  drained mid-loop).  Every inline wait is followed by sched_barrier(0) (rule #18).
//  This is the one documented escape (m196->m198: +28-41%) not yet isolated here.
// =====================================================================================

// ------- weight reorder+cast, step-linear + chunk-swizzled -------
__global__ __launch_bounds__(256)
void reorder_w2_kernel(const float* __restrict__ w, uint32_t* __restrict__ Wr) {
    const int d   = blockIdx.x;
    const int tid = threadIdx.x;
    __shared__ float wrow[3584];
    const float4* src = (const float4*)(w + (size_t)d * 3584);
    for (int e = tid; e < 896; e += 256) ((float4*)wrow)[e] = src[e];
    __syncthreads();
    const int cc  = tid >> 4;
    const int clp = tid & 15;                                   // pair index in chunk (ch 2clp,2clp+1)
    const int pos = (((clp >> 2) ^ ((d >> 1) & 3)) << 2) | (clp & 3);
    #pragma unroll
    for (int k = 0; k < K_; ++k) {
        const float w0 = wrow[tid * 14 + k];
        const float w1 = wrow[tid * 14 + 7 + k];
        Wr[((size_t)(cc * 7 + k) * 512 + d) * 16 + pos] = (f2bf(w1) << 16) | f2bf(w0);
    }
}

// ------- interp+pack: stage x slab -> LDS, interpolate ONCE, write MFMA-ready P -------
__global__ __launch_bounds__(256)
void interp_pack_kernel(const float* __restrict__ x, const float* __restrict__ offs,
                        uint32_t* __restrict__ P) {
    const int obx = blockIdx.x;   // 0..31
    const int cc  = blockIdx.y;   // 0..15
    const int b   = blockIdx.z;
    const int tid = threadIdx.x;
    const int o0  = obx * 128;
    __shared__ __align__(16) uint32_t XT[2176];   // 136 cols x 16 pair-slots (XOR-swizzled)

    // ---- phase 1: x -> XT (bf16 channel-pairs, per-column XOR on pair-group) ----
    const float* xc = x + ((size_t)b * CIN + cc * 32) * L_ + o0;
    #pragma unroll
    for (int r = 0; r < 3; ++r) {
        const int e = r * 256 + tid;
        if (e < 544) {
            const int cp   = e / 34;
            const int col4 = e - cp * 34;
            const int colb = col4 * 4;
            const float* p0 = xc + (size_t)(2 * cp) * L_ + colb;
            const float* p1 = p0 + L_;
            float4 v0, v1;
            if (o0 + colb + 3 < L_) {
                v0 = *(const float4*)p0;
                v1 = *(const float4*)p1;
            } else {
                float a0 = (o0 + colb + 0 < L_) ? p0[0] : 0.f;
                float a1 = (o0 + colb + 1 < L_) ? p0[1] : 0.f;
                float a2 = (o0 + colb + 2 < L_) ? p0[2] : 0.f;
                float a3 = (o0 + colb + 3 < L_) ? p0[3] : 0.f;
                float b0 = (o0 + colb + 0 < L_) ? p1[0] : 0.f;
                float b1 = (o0 + colb + 1 < L_) ? p1[1] : 0.f;
                float b2 = (o0 + colb + 2 < L_) ? p1[2] : 0.f;
                float b3 = (o0 + colb + 3 < L_) ? p1[3] : 0.f;
                v0 = make_float4(a0, a1, a2, a3);
                v1 = make_float4(b0, b1, b2, b3);
            }
            const float* f0 = (const float*)&v0;
            const float* f1 = (const float*)&v1;
            const int cpg = cp >> 1, hh = cp & 1;
            #pragma unroll
            for (int ii = 0; ii < 4; ++ii) {
                const int col = colb + ii;
                XT[col * 16 + (((cpg ^ (col & 7)) << 1) | hh)] = pack2bf(f0[ii], f1[ii]);
            }
        }
    }
    __syncthreads();

    // ---- phase 2: interpolate, write P slabs (chunk-swizzled for coalesced reads) ----
    const int o_loc = tid >> 1;
    const int h     = tid & 1;                    // channel half: pairs 8h..8h+7
    int o = o0 + o_loc; if (o > OUT_LEN - 1) o = OUT_LEN - 1;
    const float t0f = (float)o;
    const int sr = (o_loc >> 1) & 3;
    uint32_t* Pb = P + ((size_t)((b * 16 + cc) * 7) * 32 + obx) * 2048 + o_loc * 16;
    const int c0 = ((2 * h) ^ sr) << 2;
    const int c1 = ((2 * h + 1) ^ sr) << 2;
    #pragma unroll
    for (int k = 0; k < K_; ++k) {
        const float off = offs[((size_t)b * OUT_LEN + o) * K_ + k];
        float T = t0f + (float)k + off;
        T = fmaxf(T, t0f);
        T = fminf(T, t0f + 6.0f);
        int u0 = (int)floorf(T); if (u0 > L_ - 2) u0 = L_ - 2;
        const float g1 = T - (float)u0;           // == max(0,1-|u0+1-T|)
        const float g0 = 1.0f - g1;               // == max(0,1-|u0-T|)
        const int ul = u0 - o0;
        const uint32_t* R0 = &XT[ul * 16];
        const uint32_t* R1 = &XT[(ul + 1) * 16];
        const int s0 = ul & 7, s1 = (ul + 1) & 7;
        uint32_t ow[8];
        #pragma unroll
        for (int q = 0; q < 4; ++q) {
            const int pg = h * 4 + q;             // pair-group -> pairs 2pg,2pg+1
            const uint2 lo = *(const uint2*)&R0[(pg ^ s0) << 1];
            const uint2 hi = *(const uint2*)&R1[(pg ^ s1) << 1];
            ow[q * 2 + 0] = interp1(lo.x, hi.x, g0, g1);
            ow[q * 2 + 1] = interp1(lo.y, hi.y, g0, g1);
        }
        uint32_t* Pk = Pb + (size_t)k * 65536;    // next k-slab: 32 slabs * 2048 u32
        *(uint4*)&Pk[c0] = make_uint4(ow[0], ow[1], ow[2], ow[3]);
        *(uint4*)&Pk[c1] = make_uint4(ow[4], ow[5], ow[6], ow[7]);
    }
}

// --- GEMM: 256x128 tile, 512 thr / 8 waves of 64x64; 2-phase sandwich per K-32 slab ---
__global__ __launch_bounds__(512, 1)
void gemm_kernel(const ushort_t* __restrict__ Wr, const uint32_t* __restrict__ P,
                 const float* __restrict__ bias, float* __restrict__ out) {
    const int bxi  = blockIdx.x;                  // o-tile (128 wide), 0..31
    const int o0   = bxi * 128;
    const int d0   = blockIdx.y * 256;            // d-tile (256 wide), 0..1
    const int b    = blockIdx.z;
    const int tid  = threadIdx.x;
    const int wv   = tid >> 6;                    // 8 waves
    const int lane = tid & 63;
    const int m16  = lane & 15;
    const int quad = lane >> 4;
    const int wd   = wv >> 1;                     // d-band of wave (64 rows), 0..3
    const int wo   = wv & 1;                      // o-half of wave (64 cols), 0..1
    const int sw   = (m16 >> 1) & 3;              // == (row>>1)&3 for every fragment row
    const int chk  = (quad ^ sw) * 8;             // physical 16B chunk (ushort units)

    // 4-slab rotation: A 4x16KB + B 4x8KB = 96 KB (1 block/CU, 8 waves = 2/SIMD)
    __shared__ __align__(16) ushort_t As0[8192], As1[8192], As2[8192], As3[8192];
    __shared__ __align__(16) ushort_t Bs0[4096], Bs1[4096], Bs2[4096], Bs3[4096];

    const int aoff = (wd * 64 + m16) * 32 + chk;
    const int boff = (wo * 64 + m16) * 32 + chk;

    const ushort_t* Ag = Wr + (size_t)d0 * 32 + (size_t)tid * 8;                      // +s*16384
    const uint32_t* Bg = P + ((size_t)(b * 112) * 32 + bxi) * 2048 + (size_t)tid * 4; // +s*65536

// 3 global_load_lds per thread per slab: 2 x 8KB A-rounds + 1 x 8KB B (r7-verified)
#define ISSUE(S, ASP, BSP)                                                    \
    { _Pragma("unroll") for (int r_ = 0; r_ < 2; ++r_)                        \
        async16(Ag + (size_t)(S) * 16384 + r_ * 4096,                         \
                (void*)((ASP) + (r_ * 512 + wv * 64) * 8));                   \
      async16(Bg + (size_t)(S) * 65536,                                       \
              (void*)((BSP) + (size_t)(wv * 64) * 8)); }

// One K-32 slab in the 2-phase sandwich.  Entry invariant: slab's data is
// vmcnt-confirmed and barrier'd.  DOI/SN/ANX/BNX: optional stage of slab SN.
// VN (string): outstanding vmem ops allowed at slab end ("6" = 2 slabs in flight).
#define SLAB(ASP, BSP, DOI, SN, ANX, BNX, VN)                                 \
    {                                                                         \
        bf16x8 af_[4], bA_[2], bB_[2];                                        \
        /* ---- phase 1: read 4 A-frags + 2 B-frags, stage next, MFMA 8 ---- */ \
        _Pragma("unroll")                                                     \
        for (int i_ = 0; i_ < 4; ++i_) af_[i_] = *(const bf16x8*)&(ASP)[aoff + i_ * 512]; \
        bA_[0] = *(const bf16x8*)&(BSP)[boff];                                \
        bA_[1] = *(const bf16x8*)&(BSP)[boff + 512];                          \
        __builtin_amdgcn_sched_barrier(0);                                    \
        if (DOI) { ISSUE(SN, ANX, BNX); }                                     \
        __builtin_amdgcn_s_barrier();                                         \
        asm volatile("s_waitcnt lgkmcnt(0)" ::: "memory");                    \
        __builtin_amdgcn_sched_barrier(0);                                    \
        __builtin_amdgcn_s_setprio(1);                                        \
        _Pragma("unroll")                                                     \
        for (int i_ = 0; i_ < 4; ++i_) {                                      \
            acc[i_][0] = __builtin_amdgcn_mfma_f32_16x16x32_bf16(af_[i_], bA_[0], acc[i_][0], 0, 0, 0); \
            acc[i_][1] = __builtin_amdgcn_mfma_f32_16x16x32_bf16(af_[i_], bA_[1], acc[i_][1], 0, 0, 0); \
        }                                                                     \
        __builtin_amdgcn_s_setprio(0);                                        \
        /* ---- phase 2: read remaining 2 B-frags, MFMA 8 ---- */             \
        bB_[0] = *(const bf16x8*)&(BSP)[boff + 1024];                         \
        bB_[1] = *(const bf16x8*)&(BSP)[boff + 1536];                         \
        __builtin_amdgcn_sched_barrier(0);                                    \
        __builtin_amdgcn_s_barrier();                                         \
        asm volatile("s_waitcnt lgkmcnt(0)" ::: "memory");                    \
        __builtin_amdgcn_sched_barrier(0);                                    \
        __builtin_amdgcn_s_setprio(1);                                        \
        _Pragma("unroll")                                                     \
        for (int i_ = 0; i_ < 4; ++i_) {                                      \
            acc[i_][2] = __builtin_amdgcn_mfma_f32_16x16x32_bf16(af_[i_], bB_[0], acc[i_][2], 0, 0, 0); \
            acc[i_][3] = __builtin_amdgcn_mfma_f32_16x16x32_bf16(af_[i_], bB_[1], acc[i_][3], 0, 0, 0); \
        }                                                                     \
        __builtin_amdgcn_s_setprio(0);                                        \
        /* ---- slab end: confirm next slab (counted, never 0 mid-loop) ---- */ \
        asm volatile("s_waitcnt vmcnt(" VN ")" ::: "memory");                 \
        __builtin_amdgcn_s_barrier();                                         \
        __builtin_amdgcn_sched_barrier(0);                                    \
    }

    f32x4 acc[4][4];
    #pragma unroll
    for (int i = 0; i < 4; ++i) {
        #pragma unroll
        for (int j = 0; j < 4; ++j) acc[i][j] = (f32x4){0.f, 0.f, 0.f, 0.f};
    }

    // prologue: slabs 0,1,2 in flight (9 ops/thread); confirm slab 0 (6 left)
    ISSUE(0, As0, Bs0);
    ISSUE(1, As1, Bs1);
    ISSUE(2, As2, Bs2);
    asm volatile("s_waitcnt vmcnt(6)" ::: "memory");
    __builtin_amdgcn_s_barrier();
    __builtin_amdgcn_sched_barrier(0);

    // steady state: slab s issues stage(s+3) (distance 3, 2 slabs always in flight).
    // WAR: stage(s+3) targets buf[(s-1)&3]; its reads retired at slab s-1's
    // lgkmcnt(0) and are block-wide ordered by the end-of-slab barrier.
    #pragma unroll 1
    for (int t = 0; t < 108; t += 4) {
        SLAB(As0, Bs0, 1, t + 3, As3, Bs3, "6")
        SLAB(As1, Bs1, 1, t + 4, As0, Bs0, "6")
        SLAB(As2, Bs2, 1, t + 5, As1, Bs1, "6")
        SLAB(As3, Bs3, 1, t + 6, As2, Bs2, "6")
    }
    // peel: slabs 108..111 (loop issued through 110; 108 issues 111)
    SLAB(As0, Bs0, 1, 111, As3, Bs3, "6")     // slab 108 -> confirm 109
    SLAB(As1, Bs1, 0, 0, As0, Bs0, "3")       // slab 109 -> confirm 110
    SLAB(As2, Bs2, 0, 0, As0, Bs0, "0")       // slab 110 -> confirm 111
    SLAB(As3, Bs3, 0, 0, As0, Bs0, "0")       // slab 111

    // epilogue (verified C/D layout: col=o (m16), row=quad*4+r on the d dim)
    #pragma unroll
    for (int i = 0; i < 4; ++i) {
        const int dd = d0 + wd * 64 + i * 16 + quad * 4;
        float bv[4];
        #pragma unroll
        for (int r = 0; r < 4; ++r) bv[r] = bias[dd + r];
        #pragma unroll
        for (int j = 0; j < 4; ++j) {
            const int oo = o0 + wo * 64 + j * 16 + m16;
            if (oo < OUT_LEN) {
                float* op = out + (size_t)b * COUT * OUT_LEN + (size_t)dd * OUT_LEN + oo;
                #pragma unroll
                for (int r = 0; r < 4; ++r)
                    op[(size_t)r * OUT_LEN] = acc[i][j][r] + bv[r];
            }
        }
    }
#undef ISSUE
#undef SLAB
}

// =====================================================================================
//  OLD PATH (verified @186.9us) — used when ws is too small for P (117 MB)
// =====================================================================================

__global__ __launch_bounds__(256)
void reorder_w1_kernel(const float* __restrict__ w, uint32_t* __restrict__ Wr) {
    const int d   = blockIdx.x;
    const int tid = threadIdx.x;
    __shared__ float wrow[3584];
    const float4* src = (const float4*)(w + (size_t)d * 3584);
    for (int e = tid; e < 896; e += 256) ((float4*)wrow)[e] = src[e];
    __syncthreads();
    const int cc  = tid >> 4;
    const int clp = tid & 15;
    #pragma unroll
    for (int k = 0; k < K_; ++k) {
        const float w0 = wrow[tid * 14 + k];
        const float w1 = wrow[tid * 14 + 7 + k];
        Wr[((size_t)((k * 16 + cc) * 512 + d)) * 16 + clp] = (f2bf(w1) << 16) | f2bf(w0);
    }
}

__global__ __launch_bounds__(256)
void prepack_kernel(const float* __restrict__ x, uint32_t* __restrict__ xpack) {
    const int obx = blockIdx.x;   // 0..31
    const int cc  = blockIdx.y;   // 0..15
    const int b   = blockIdx.z;
    const int tid = threadIdx.x;
    const int o0  = obx * 128;
    __shared__ __align__(16) uint32_t XT[2176];
    const float* xc = x + ((size_t)b * CIN + cc * 32) * L_ + o0;
    #pragma unroll
    for (int r = 0; r < 3; ++r) {
        const int e = r * 256 + tid;
        if (e < 544) {
            const int cp   = e / 34;
            const int col4 = e - cp * 34;
            const int colb = col4 * 4;
            const float* p0 = xc + (size_t)(2 * cp) * L_ + colb;
            const float* p1 = p0 + L_;
            float4 v0, v1;
            if (o0 + colb + 3 < L_) {
                v0 = *(const float4*)p0;
                v1 = *(const float4*)p1;
            } else {
                float a0 = (o0 + colb + 0 < L_) ? p0[0] : 0.f;
                float a1 = (o0 + colb + 1 < L_) ? p0[1] : 0.f;
                float a2 = (o0 + colb + 2 < L_) ? p0[2] : 0.f;
                float a3 = (o0 + colb + 3 < L_) ? p0[3] : 0.f;
                float b0 = (o0 + colb + 0 < L_) ? p1[0] : 0.f;
                float b1 = (o0 + colb + 1 < L_) ? p1[1] : 0.f;
                float b2 = (o0 + colb + 2 < L_) ? p1[2] : 0.f;
                float b3 = (o0 + colb + 3 < L_) ? p1[3] : 0.f;
                v0 = make_float4(a0, a1, a2, a3);
                v1 = make_float4(b0, b1, b2, b3);
            }
            const float* f0 = (const float*)&v0;
            const float* f1 = (const float*)&v1;
            const int cpg = cp >> 1, h = cp & 1;
            #pragma unroll
            for (int ii = 0; ii < 4; ++ii) {
                const int col = colb + ii;
                XT[col * 16 + (((cpg ^ (col & 7)) << 1) | h)] = pack2bf(f0[ii], f1[ii]);
            }
        }
    }
    __syncthreads();
    uint4* dst = (uint4*)xpack + (size_t)((b * 16 + cc) * 32 + obx) * 544;
    const uint4* s4 = (const uint4*)XT;
    #pragma unroll
    for (int r = 0; r < 3; ++r) {
        const int e = r * 256 + tid;
        if (e < 544) dst[e] = s4[e];
    }
}

__global__ __launch_bounds__(256, 2)
void fused_v1_kernel(const float* __restrict__ offs, const ushort_t* __restrict__ Wr,
                     const uint32_t* __restrict__ xpack, const float* __restrict__ bias,
                     float* __restrict__ out) {
    const int bxi  = blockIdx.x;
    const int o0   = bxi * 128;
    const int d0   = blockIdx.y * 128;
    const int b    = blockIdx.z;
    const int tid  = threadIdx.x;
    const int wv   = tid >> 6;
    const int lane = tid & 63;
    const int m16  = lane & 15;
    const int quad = lane >> 4;
    const int ob   = wv * 32;
    const int q2   = quad * 2;

    __shared__ __align__(16) ushort_t As0[4096], As1[4096], As2[4096], As3[4096];
    __shared__ __align__(16) uint32_t XTB0[2304], XTB1[2304];
    __shared__ int    SU[896];
    __shared__ float2 PG[896];

#define ISSUE_A(KK, CC, ASP)                                                      \
    {                                                                             \
        _Pragma("unroll")                                                         \
        for (int r_ = 0; r_ < 2; ++r_) {                                          \
            const int c_ = r_ * 256 + tid;                                        \
            const int row_ = c_ >> 2, pc_ = c_ & 3;                               \
            const ushort_t* g_ = Wr                                               \
                + ((size_t)(((KK) * 16 + (CC)) * 512 + d0 + row_)) * 32 + pc_ * 8;\
            async16(g_, (void*)((ASP) + (r_ * 256 + wv * 64) * 8));               \
        }                                                                         \
    }

#define ISSUE_XTB(CC, XP)                                                         \
    {                                                                             \
        const uint32_t* sp_ = xpack + ((size_t)((b * 16 + (CC)) * 32 + bxi)) * 2176; \
        _Pragma("unroll")                                                         \
        for (int r_ = 0; r_ < 3; ++r_) {                                          \
            const int cb_ = r_ * 256 + wv * 64;                                   \
            if (cb_ < 544) {                                                      \
                const int c_ = r_ * 256 + tid;                                    \
                async16((const void*)(sp_ + (size_t)c_ * 4),                      \
                        (void*)((XP) + (size_t)cb_ * 4));                         \
            }                                                                     \
        }                                                                         \
    }

#define STEP(KK, XP, ASP)                                                         \
    {                                                                             \
        bf16x8 af_[8];                                                            \
        _Pragma("unroll")                                                         \
        for (int i_ = 0; i_ < 8; ++i_)                                            \
            af_[i_] = *(const bf16x8*)&(ASP)[(i_ * 16 + m16) * 32 + quad * 8];    \
        bf16x8 bfr_[2];                                                           \
        _Pragma("unroll")                                                         \
        for (int j_ = 0; j_ < 2; ++j_) {                                          \
            const int row_ = ((KK) << 7) | (ob + j_ * 16 + m16);                  \
            const int u_ = SU[row_];                                              \
            const float2 g_ = PG[row_];                                           \
            const uint32_t* Xr0_ = &(XP)[u_ * 16];                                \
            const uint32_t* Xr1_ = Xr0_ + 16;                                     \
            const int s0_ = u_ & 7, s1_ = (u_ + 1) & 7;                           \
            const uint2 a0_ = *(const uint2*)&Xr0_[((q2     ^ s0_) << 1)];        \
            const uint2 a1_ = *(const uint2*)&Xr0_[(((q2+1) ^ s0_) << 1)];        \
            const uint2 c0_ = *(const uint2*)&Xr1_[((q2     ^ s1_) << 1)];        \
            const uint2 c1_ = *(const uint2*)&Xr1_[(((q2+1) ^ s1_) << 1)];        \
            uint4 rr_;                                                            \
            rr_.x = interp1(a0_.x, c0_.x, g_.x, g_.y);                            \
            rr_.y = interp1(a0_.y, c0_.y, g_.x, g_.y);                            \
            rr_.z = interp1(a1_.x, c1_.x, g_.x, g_.y);                            \
            rr_.w = interp1(a1_.y, c1_.y, g_.x, g_.y);                            \
            __builtin_memcpy(&bfr_[j_], &rr_, 16);                                \
        }                                                                         \
        _Pragma("unroll")                                                         \
        for (int i_ = 0; i_ < 8; ++i_) {                                          \
            _Pragma("unroll")                                                     \
            for (int j_ = 0; j_ < 2; ++j_)                                        \
                acc[i_][j_] = __builtin_amdgcn_mfma_f32_16x16x32_bf16(af_[i_], bfr_[j_], acc[i_][j_], 0, 0, 0); \
        }                                                                         \
    }

#define HALF(CCB, A0_, A1_, A2_, A3_)                                             \
    ISSUE_A(2, (CCB), A2_); ISSUE_A(3, (CCB), A3_); ISSUE_XTB((CCB) + 1, XTB1);   \
    STEP(0, XTB0, A0_); STEP(1, XTB0, A1_); __syncthreads();                      \
    ISSUE_A(4, (CCB), A0_); ISSUE_A(5, (CCB), A1_);                               \
    STEP(2, XTB0, A2_); STEP(3, XTB0, A3_); __syncthreads();                      \
    ISSUE_A(6, (CCB), A2_); ISSUE_A(0, (CCB) + 1, A3_);                           \
    STEP(4, XTB0, A0_); STEP(5, XTB0, A1_); __syncthreads();                      \
    ISSUE_A(1, (CCB) + 1, A0_); ISSUE_A(2, (CCB) + 1, A1_);                       \
    STEP(6, XTB0, A2_); STEP(0, XTB1, A3_); __syncthreads();                      \
    ISSUE_A(3, (CCB) + 1, A2_); ISSUE_A(4, (CCB) + 1, A3_);                       \
    if ((CCB) + 2 < 16) { ISSUE_XTB((CCB) + 2, XTB0); }                           \
    STEP(1, XTB1, A0_); STEP(2, XTB1, A1_); __syncthreads();                      \
    ISSUE_A(5, (CCB) + 1, A0_); ISSUE_A(6, (CCB) + 1, A1_);                       \
    STEP(3, XTB1, A2_); STEP(4, XTB1, A3_); __syncthreads();                      \
    if ((CCB) + 2 < 16) { ISSUE_A(0, (CCB) + 2, A2_); ISSUE_A(1, (CCB) + 2, A3_); } \
    STEP(5, XTB1, A0_); STEP(6, XTB1, A1_); __syncthreads();

    f32x4 acc[8][2];
    #pragma unroll
    for (int i = 0; i < 8; ++i) {
        #pragma unroll
        for (int j = 0; j < 2; ++j) acc[i][j] = (f32x4){0.f, 0.f, 0.f, 0.f};
    }

    ISSUE_XTB(0, XTB0);
    ISSUE_A(0, 0, As0);
    ISSUE_A(1, 0, As1);
    for (int e = tid; e < 896; e += 256) {
        const int k  = e >> 7;
        const int ol = e & 127;
        int o = o0 + ol; if (o > OUT_LEN - 1) o = OUT_LEN - 1;
        const float t0  = (float)o;
        const float off = offs[((size_t)b * OUT_LEN + o) * K_ + k];
        float T = t0 + (float)k + off;
        T = fmaxf(T, t0);
        T = fminf(T, t0 + 6.0f);
        int u0 = (int)floorf(T);
        if (u0 > L_ - 2) u0 = L_ - 2;
        const float g0 = fmaxf(1.0f - fabsf((float)u0 - T), 0.0f);
        const float g1 = fmaxf(1.0f - fabsf((float)(u0 + 1) - T), 0.0f);
        SU[e] = u0 - o0;
        PG[e] = make_float2(g0, g1);
    }
    __syncthreads();

    #pragma unroll 1
    for (int s4 = 0; s4 < 16; s4 += 4) {
        HALF(s4,     As0, As1, As2, As3)
        HALF(s4 + 2, As2, As3, As0, As1)
    }

    #pragma unroll
    for (int i = 0; i < 8; ++i) {
        const int dd = d0 + i * 16 + quad * 4;
        float bv[4];
        #pragma unroll
        for (int r = 0; r < 4; ++r) bv[r] = bias[dd + r];
        #pragma unroll
        for (int j = 0; j < 2; ++j) {
            const int oo = o0 + ob + j * 16 + m16;
            if (oo < OUT_LEN) {
                float* op = out + (size_t)b * COUT * OUT_LEN + (size_t)dd * OUT_LEN + oo;
                #pragma unroll
                for (int r = 0; r < 4; ++r)
                    op[(size_t)r * OUT_LEN] = acc[i][j][r] + bv[r];
            }
        }
    }
#undef ISSUE_A
#undef ISSUE_XTB
#undef STEP
#undef HALF
}

// ---------------- fp32 fallback (round-1 kernel, used only if ws too small) ----------------
#define BM 64
#define BN 64
#define BC 8
#define TT (BC * K_)

__global__ __launch_bounds__(256, 2)
void deform_conv1d_fallback(const float* __restrict__ x, const float* __restrict__ offsets,
                            const float* __restrict__ weight, const float* __restrict__ bias,
                            float* __restrict__ out) {
    const int o0 = blockIdx.x * BN, d0 = blockIdx.y * BM, b = blockIdx.z, tid = threadIdx.x;
    __shared__ int   SU[BN * K_];
    __shared__ float SG0[BN * K_], SG1[BN * K_];
    __shared__ float XT[BC][BN + 8];
    __shared__ float S[BC][K_][BN];
    __shared__ float WT[BM][TT + 1];
    for (int e = tid; e < BN * K_; e += 256) {
        const int ol = e / K_, k = e % K_, o = o0 + ol;
        int u0rel = 0; float g0 = 0.f, g1 = 0.f;
        if (o < OUT_LEN) {
            const float t0 = (float)o;
            const float off = offsets[(size_t)b * OUT_LEN * K_ + (size_t)o * K_ + k];
            float T = fminf(fmaxf(t0 + (float)k + off, t0), t0 + 6.0f);
            int u0 = (int)floorf(T); if (u0 > L_ - 2) u0 = L_ - 2;
            g0 = fmaxf(1.0f - fabsf((float)u0 - T), 0.0f);
            g1 = fmaxf(1.0f - fabsf((float)(u0 + 1) - T), 0.0f);
            u0rel = u0 - o0;
        }
        SU[e] = u0rel; SG0[e] = g0; SG1[e] = g1;
    }
    float acc[4][4];
    #pragma unroll
    for (int i = 0; i < 4; ++i) {
        #pragma unroll
        for (int j = 0; j < 4; ++j) acc[i][j] = 0.f;
    }
    const int ty = tid >> 4, tx = tid & 15;
    const float* xb = x + (size_t)b * CIN * L_;
    for (int c0 = 0; c0 < CIN; c0 += BC) {
        __syncthreads();
        for (int e = tid; e < BC * (BN + 7); e += 256) {
            const int cl = e / (BN + 7), j = e % (BN + 7), pos = o0 + j;
            XT[cl][j] = (pos < L_) ? xb[(size_t)(c0 + cl) * L_ + pos] : 0.f;
        }
        for (int e = tid; e < BM * TT; e += 256) {
            const int d = e / TT, t = e % TT;
            WT[d][t] = weight[(size_t)(d0 + d) * (CIN * K_) + c0 * K_ + t];
        }
        __syncthreads();
        for (int e = tid; e < BC * K_ * BN; e += 256) {
            const int cl = e / (K_ * BN), r = e % (K_ * BN), k = r / BN, ol = r % BN;
            const int p = ol * K_ + k, u = SU[p];
            S[cl][k][ol] = SG0[p] * XT[cl][u] + SG1[p] * XT[cl][u + 1];
        }
        __syncthreads();
        #pragma unroll
        for (int t = 0; t < TT; ++t) {
            const int cl = t / K_, k = t % K_;
            const float4 s4 = *(const float4*)&S[cl][k][tx * 4];
            const float w0 = WT[ty * 4 + 0][t], w1 = WT[ty * 4 + 1][t];
            const float w2 = WT[ty * 4 + 2][t], w3 = WT[ty * 4 + 3][t];
            acc[0][0] += w0 * s4.x; acc[0][1] += w0 * s4.y; acc[0][2] += w0 * s4.z; acc[0][3] += w0 * s4.w;
            acc[1][0] += w1 * s4.x; acc[1][1] += w1 * s4.y; acc[1][2] += w1 * s4.z; acc[1][3] += w1 * s4.w;
            acc[2][0] += w2 * s4.x; acc[2][1] += w2 * s4.y; acc[2][2] += w2 * s4.z; acc[2][3] += w2 * s4.w;
            acc[3][0] += w3 * s4.x; acc[3][1] += w3 * s4.y; acc[3][2] += w3 * s4.z; acc[3][3] += w3 * s4.w;
        }
    }
    #pragma unroll
    for (int i = 0; i < 4; ++i) {
        const int d = d0 + ty * 4 + i;
        const float bvv = bias[d];
        #pragma unroll
        for (int j = 0; j < 4; ++j) {
            const int o = o0 + tx * 4 + j;
            if (o < OUT_LEN)
                out[(size_t)b * COUT * OUT_LEN + (size_t)d * OUT_LEN + o] = acc[i][j] + bvv;
        }
    }
}

extern "C" void kernel_launch(void* const* d_in, const int* in_sizes, int n_in,
                              void* d_out, int out_size, void* d_ws, size_t ws_size,
                              hipStream_t stream) {
    const float* x       = (const float*)d_in[0];
    const float* offsets = (const float*)d_in[1];
    const float* weight  = (const float*)d_in[2];
    const float* bias    = (const float*)d_in[3];
    float* out = (float*)d_out;

    const size_t WR_BYTES = (size_t)512 * 512 * 7 * 2;                  // 3,670,016
    const size_t P_BYTES  = (size_t)4 * 16 * 7 * 32 * 8192;             // 117,440,512
    const size_t XP_BYTES = (size_t)2048 * 544 * 16 + 512;              // 17,826,304

    if (ws_size >= WR_BYTES + P_BYTES) {
        // new path: precomputed interp + 2-phase-sandwich counted-vmcnt GEMM
        uint32_t* Wr_u32 = (uint32_t*)d_ws;
        ushort_t* Wr     = (ushort_t*)d_ws;
        uint32_t* P      = (uint32_t*)((char*)d_ws + WR_BYTES);
        reorder_w2_kernel<<<512, 256, 0, stream>>>(weight, Wr_u32);
        interp_pack_kernel<<<dim3(32, 16, B_), 256, 0, stream>>>(x, offsets, P);
        gemm_kernel<<<dim3(32, 2, B_), 512, 0, stream>>>(Wr, P, bias, out);
        return;
    }

    if (ws_size >= WR_BYTES + XP_BYTES) {
        // old verified path
        uint32_t* Wr_u32 = (uint32_t*)d_ws;
        ushort_t* Wr     = (ushort_t*)d_ws;
        uint32_t* xpack  = (uint32_t*)((char*)d_ws + WR_BYTES);
        reorder_w1_kernel<<<512, 256, 0, stream>>>(weight, Wr_u32);
        prepack_kernel<<<dim3(32, 16, B_), 256, 0, stream>>>(x, xpack);
        fused_v1_kernel<<<dim3(32, 4, B_), 256, 0, stream>>>(offsets, Wr, xpack, bias, out);
        return;
    }

    dim3 grid((OUT_LEN + BN - 1) / BN, COUT / BM, B_);
    deform_conv1d_fallback<<<grid, 256, 0, stream>>>(x, offsets, weight, bias, out);
}

// Round 12
// 168.895 us; speedup vs baseline: 1.0217x; 1.0217x over previous
//
#include <hip/hip_runtime.h>
#include <hip/hip_bf16.h>
#include <stdint.h>

#define B_      4
#define CIN     512
#define COUT    512
#define L_      4096
#define K_      7
#define OUT_LEN 4090

typedef unsigned short ushort_t;
typedef __attribute__((ext_vector_type(8))) __bf16 bf16x8;
typedef __attribute__((ext_vector_type(4))) float f32x4;

__device__ __forceinline__ uint32_t f2bf(float f) {
    uint32_t u = __float_as_uint(f);
    return (u + 0x7fffu + ((u >> 16) & 1u)) >> 16;
}

__device__ __forceinline__ uint32_t pack2bf(float s0, float s1) {   // s0 -> low 16
    __hip_bfloat162 h = __float22bfloat162_rn(make_float2(s0, s1));
    uint32_t r;
    __builtin_memcpy(&r, &h, 4);
    return r;
}

__device__ __forceinline__ uint32_t interp1(uint32_t wl, uint32_t wh, float g0, float g1) {
    const float l0 = __uint_as_float(wl << 16);
    const float l1 = __uint_as_float(wl & 0xffff0000u);
    const float h0 = __uint_as_float(wh << 16);
    const float h1 = __uint_as_float(wh & 0xffff0000u);
    return pack2bf(g0 * l0 + g1 * h0, g0 * l1 + g1 * h1);
}

__device__ __forceinline__ void async16(const void* g, void* l) {
    __builtin_amdgcn_global_load_lds(
        (const __attribute__((address_space(1))) unsigned int*)g,
        (__attribute__((address_space(3))) unsigned int*)l, 16, 0, 0);
}

// =====================================================================================
//  NEW PATH
//  Layouts (step s = cc*7 + k, s = 0..111):
//   Wr: slab s -> 512 d-rows x 32 bf16 (channels cc*32..+31), 64 B/row,
//       16B-chunk c stored at physical chunk c ^ ((d>>1)&3)      [pre-swizzled]
//   P : slab (s, b, obx) -> 128 o-rows x 32 bf16, 64 B/row,
//       chunk c stored at physical chunk c ^ ((o_loc>>1)&3)      [pre-swizzled]
//  gemm (round 12): 2-phase SANDWICH (r11, best: 64.7us) on r4's 128x128 geometry
//  with 2 INDEPENDENT blocks/CU (r4's cross-block overlap, +2.4us over 1x8w).
//  Completes the {schedule} x {block config} 2x2: sandwich trims barrier-drain
//  exposure; the co-resident block fills the remaining sync stalls.
//  4-slab K=32 rotation, 4 DMA ops/thread/slab, slab-end counted vmcnt(8)
//  (2 slabs in flight, never drained mid-loop), every wait + sched_barrier(0).
// =====================================================================================

// ------- weight reorder+cast, step-linear + chunk-swizzled -------
__global__ __launch_bounds__(256)
void reorder_w2_kernel(const float* __restrict__ w, uint32_t* __restrict__ Wr) {
    const int d   = blockIdx.x;
    const int tid = threadIdx.x;
    __shared__ float wrow[3584];
    const float4* src = (const float4*)(w + (size_t)d * 3584);
    for (int e = tid; e < 896; e += 256) ((float4*)wrow)[e] = src[e];
    __syncthreads();
    const int cc  = tid >> 4;
    const int clp = tid & 15;                                   // pair index in chunk (ch 2clp,2clp+1)
    const int pos = (((clp >> 2) ^ ((d >> 1) & 3)) << 2) | (clp & 3);
    #pragma unroll
    for (int k = 0; k < K_; ++k) {
        const float w0 = wrow[tid * 14 + k];
        const float w1 = wrow[tid * 14 + 7 + k];
        Wr[((size_t)(cc * 7 + k) * 512 + d) * 16 + pos] = (f2bf(w1) << 16) | f2bf(w0);
    }
}

// ------- interp+pack: stage x slab -> LDS, interpolate ONCE, write MFMA-ready P -------
__global__ __launch_bounds__(256)
void interp_pack_kernel(const float* __restrict__ x, const float* __restrict__ offs,
                        uint32_t* __restrict__ P) {
    const int obx = blockIdx.x;   // 0..31
    const int cc  = blockIdx.y;   // 0..15
    const int b   = blockIdx.z;
    const int tid = threadIdx.x;
    const int o0  = obx * 128;
    __shared__ __align__(16) uint32_t XT[2176];   // 136 cols x 16 pair-slots (XOR-swizzled)

    // ---- phase 1: x -> XT (bf16 channel-pairs, per-column XOR on pair-group) ----
    const float* xc = x + ((size_t)b * CIN + cc * 32) * L_ + o0;
    #pragma unroll
    for (int r = 0; r < 3; ++r) {
        const int e = r * 256 + tid;
        if (e < 544) {
            const int cp   = e / 34;
            const int col4 = e - cp * 34;
            const int colb = col4 * 4;
            const float* p0 = xc + (size_t)(2 * cp) * L_ + colb;
            const float* p1 = p0 + L_;
            float4 v0, v1;
            if (o0 + colb + 3 < L_) {
                v0 = *(const float4*)p0;
                v1 = *(const float4*)p1;
            } else {
                float a0 = (o0 + colb + 0 < L_) ? p0[0] : 0.f;
                float a1 = (o0 + colb + 1 < L_) ? p0[1] : 0.f;
                float a2 = (o0 + colb + 2 < L_) ? p0[2] : 0.f;
                float a3 = (o0 + colb + 3 < L_) ? p0[3] : 0.f;
                float b0 = (o0 + colb + 0 < L_) ? p1[0] : 0.f;
                float b1 = (o0 + colb + 1 < L_) ? p1[1] : 0.f;
                float b2 = (o0 + colb + 2 < L_) ? p1[2] : 0.f;
                float b3 = (o0 + colb + 3 < L_) ? p1[3] : 0.f;
                v0 = make_float4(a0, a1, a2, a3);
                v1 = make_float4(b0, b1, b2, b3);
            }
            const float* f0 = (const float*)&v0;
            const float* f1 = (const float*)&v1;
            const int cpg = cp >> 1, hh = cp & 1;
            #pragma unroll
            for (int ii = 0; ii < 4; ++ii) {
                const int col = colb + ii;
                XT[col * 16 + (((cpg ^ (col & 7)) << 1) | hh)] = pack2bf(f0[ii], f1[ii]);
            }
        }
    }
    __syncthreads();

    // ---- phase 2: interpolate, write P slabs (chunk-swizzled for coalesced reads) ----
    const int o_loc = tid >> 1;
    const int h     = tid & 1;                    // channel half: pairs 8h..8h+7
    int o = o0 + o_loc; if (o > OUT_LEN - 1) o = OUT_LEN - 1;
    const float t0f = (float)o;
    const int sr = (o_loc >> 1) & 3;
    uint32_t* Pb = P + ((size_t)((b * 16 + cc) * 7) * 32 + obx) * 2048 + o_loc * 16;
    const int c0 = ((2 * h) ^ sr) << 2;
    const int c1 = ((2 * h + 1) ^ sr) << 2;
    #pragma unroll
    for (int k = 0; k < K_; ++k) {
        const float off = offs[((size_t)b * OUT_LEN + o) * K_ + k];
        float T = t0f + (float)k + off;
        T = fmaxf(T, t0f);
        T = fminf(T, t0f + 6.0f);
        int u0 = (int)floorf(T); if (u0 > L_ - 2) u0 = L_ - 2;
        const float g1 = T - (float)u0;           // == max(0,1-|u0+1-T|)
        const float g0 = 1.0f - g1;               // == max(0,1-|u0-T|)
        const int ul = u0 - o0;
        const uint32_t* R0 = &XT[ul * 16];
        const uint32_t* R1 = &XT[(ul + 1) * 16];
        const int s0 = ul & 7, s1 = (ul + 1) & 7;
        uint32_t ow[8];
        #pragma unroll
        for (int q = 0; q < 4; ++q) {
            const int pg = h * 4 + q;             // pair-group -> pairs 2pg,2pg+1
            const uint2 lo = *(const uint2*)&R0[(pg ^ s0) << 1];
            const uint2 hi = *(const uint2*)&R1[(pg ^ s1) << 1];
            ow[q * 2 + 0] = interp1(lo.x, hi.x, g0, g1);
            ow[q * 2 + 1] = interp1(lo.y, hi.y, g0, g1);
        }
        uint32_t* Pk = Pb + (size_t)k * 65536;    // next k-slab: 32 slabs * 2048 u32
        *(uint4*)&Pk[c0] = make_uint4(ow[0], ow[1], ow[2], ow[3]);
        *(uint4*)&Pk[c1] = make_uint4(ow[4], ow[5], ow[6], ow[7]);
    }
}

// --- GEMM: 128x128 tile, 4 waves, 2 blocks/CU; 2-phase sandwich per K-32 slab ---
__global__ __launch_bounds__(256, 2)
void gemm_kernel(const ushort_t* __restrict__ Wr, const uint32_t* __restrict__ P,
                 const float* __restrict__ bias, float* __restrict__ out) {
    const int bxi  = blockIdx.x;
    const int o0   = bxi * 128;
    const int d0   = blockIdx.y * 128;
    const int b    = blockIdx.z;
    const int tid  = threadIdx.x;
    const int wv   = tid >> 6;
    const int lane = tid & 63;
    const int m16  = lane & 15;
    const int quad = lane >> 4;
    const int wd   = wv >> 1;                     // d-half of wave
    const int wo   = wv & 1;                      // o-half of wave
    const int sw   = (m16 >> 1) & 3;              // == (row>>1)&3 for every fragment row
    const int chk  = (quad ^ sw) * 8;             // physical 16B chunk (ushort units)

    // 4-slab rotation: A 4x8KB + B 4x8KB = 64 KB -> 2 blocks/CU
    __shared__ __align__(16) ushort_t As0[4096], As1[4096], As2[4096], As3[4096];
    __shared__ __align__(16) ushort_t Bs0[4096], Bs1[4096], Bs2[4096], Bs3[4096];

    const int aoff = (wd * 64 + m16) * 32 + chk;
    const int boff = (wo * 64 + m16) * 32 + chk;

    const ushort_t* Ag = Wr + (size_t)d0 * 32 + (size_t)tid * 8;                      // +s*16384
    const uint32_t* Bg = P + ((size_t)(b * 112) * 32 + bxi) * 2048 + (size_t)tid * 4; // +s*65536

// 4 global_load_lds per thread per slab (2 A + 2 B) -- r4-verified addressing
#define ISSUE(S, ASP, BSP)                                                    \
    { _Pragma("unroll") for (int r_ = 0; r_ < 2; ++r_)                        \
        async16(Ag + (size_t)(S) * 16384 + r_ * 2048,                         \
                (void*)((ASP) + (r_ * 256 + wv * 64) * 8));                   \
      _Pragma("unroll") for (int r_ = 0; r_ < 2; ++r_)                        \
        async16(Bg + (size_t)(S) * 65536 + r_ * 1024,                         \
                (void*)((BSP) + (r_ * 256 + wv * 64) * 8)); }

// One K-32 slab, 2-phase sandwich.  Entry invariant: slab data vmcnt-confirmed
// and barrier'd.  DOI/SN/ANX/BNX: optional stage of slab SN (distance 3).
// VN (string): outstanding vmem ops allowed at slab end ("8" = 2 slabs in flight).
#define SLAB(ASP, BSP, DOI, SN, ANX, BNX, VN)                                 \
    {                                                                         \
        bf16x8 af_[4], bA_[2], bB_[2];                                        \
        /* ---- phase 1: read 4 A-frags + 2 B-frags, stage next, MFMA 8 ---- */ \
        _Pragma("unroll")                                                     \
        for (int i_ = 0; i_ < 4; ++i_) af_[i_] = *(const bf16x8*)&(ASP)[aoff + i_ * 512]; \
        bA_[0] = *(const bf16x8*)&(BSP)[boff];                                \
        bA_[1] = *(const bf16x8*)&(BSP)[boff + 512];                          \
        __builtin_amdgcn_sched_barrier(0);                                    \
        if (DOI) { ISSUE(SN, ANX, BNX); }                                     \
        __builtin_amdgcn_s_barrier();                                         \
        asm volatile("s_waitcnt lgkmcnt(0)" ::: "memory");                    \
        __builtin_amdgcn_sched_barrier(0);                                    \
        __builtin_amdgcn_s_setprio(1);                                        \
        _Pragma("unroll")                                                     \
        for (int i_ = 0; i_ < 4; ++i_) {                                      \
            acc[i_][0] = __builtin_amdgcn_mfma_f32_16x16x32_bf16(af_[i_], bA_[0], acc[i_][0], 0, 0, 0); \
            acc[i_][1] = __builtin_amdgcn_mfma_f32_16x16x32_bf16(af_[i_], bA_[1], acc[i_][1], 0, 0, 0); \
        }                                                                     \
        __builtin_amdgcn_s_setprio(0);                                        \
        /* ---- phase 2: read remaining 2 B-frags, MFMA 8 ---- */             \
        bB_[0] = *(const bf16x8*)&(BSP)[boff + 1024];                         \
        bB_[1] = *(const bf16x8*)&(BSP)[boff + 1536];                         \
        __builtin_amdgcn_sched_barrier(0);                                    \
        __builtin_amdgcn_s_barrier();                                         \
        asm volatile("s_waitcnt lgkmcnt(0)" ::: "memory");                    \
        __builtin_amdgcn_sched_barrier(0);                                    \
        __builtin_amdgcn_s_setprio(1);                                        \
        _Pragma("unroll")                                                     \
        for (int i_ = 0; i_ < 4; ++i_) {                                      \
            acc[i_][2] = __builtin_amdgcn_mfma_f32_16x16x32_bf16(af_[i_], bB_[0], acc[i_][2], 0, 0, 0); \
            acc[i_][3] = __builtin_amdgcn_mfma_f32_16x16x32_bf16(af_[i_], bB_[1], acc[i_][3], 0, 0, 0); \
        }                                                                     \
        __builtin_amdgcn_s_setprio(0);                                        \
        /* ---- slab end: confirm next slab (counted, never 0 mid-loop) ---- */ \
        asm volatile("s_waitcnt vmcnt(" VN ")" ::: "memory");                 \
        __builtin_amdgcn_s_barrier();                                         \
        __builtin_amdgcn_sched_barrier(0);                                    \
    }

    f32x4 acc[4][4];
    #pragma unroll
    for (int i = 0; i < 4; ++i) {
        #pragma unroll
        for (int j = 0; j < 4; ++j) acc[i][j] = (f32x4){0.f, 0.f, 0.f, 0.f};
    }

    // prologue: slabs 0,1,2 in flight (12 ops/thread); confirm slab 0 (8 left)
    ISSUE(0, As0, Bs0);
    ISSUE(1, As1, Bs1);
    ISSUE(2, As2, Bs2);
    asm volatile("s_waitcnt vmcnt(8)" ::: "memory");
    __builtin_amdgcn_s_barrier();
    __builtin_amdgcn_sched_barrier(0);

    // steady state: slab s issues stage(s+3) (distance 3, 2 slabs in flight).
    // WAR: stage(s+3) targets buf[(s-1)&3]; its reads retired at slab s-1's
    // lgkmcnt(0) and are block-wide ordered by the end-of-slab barrier.
    #pragma unroll 1
    for (int t = 0; t < 108; t += 4) {
        SLAB(As0, Bs0, 1, t + 3, As3, Bs3, "8")
        SLAB(As1, Bs1, 1, t + 4, As0, Bs0, "8")
        SLAB(As2, Bs2, 1, t + 5, As1, Bs1, "8")
        SLAB(As3, Bs3, 1, t + 6, As2, Bs2, "8")
    }
    // peel: slabs 108..111 (loop issued through 110; 108 issues 111)
    SLAB(As0, Bs0, 1, 111, As3, Bs3, "8")     // slab 108 -> confirm 109
    SLAB(As1, Bs1, 0, 0, As0, Bs0, "4")       // slab 109 -> confirm 110
    SLAB(As2, Bs2, 0, 0, As0, Bs0, "0")       // slab 110 -> confirm 111
    SLAB(As3, Bs3, 0, 0, As0, Bs0, "0")       // slab 111

    // epilogue (verified C/D layout: col=o (m16), row=quad*4+r on the d dim)
    #pragma unroll
    for (int i = 0; i < 4; ++i) {
        const int dd = d0 + wd * 64 + i * 16 + quad * 4;
        float bv[4];
        #pragma unroll
        for (int r = 0; r < 4; ++r) bv[r] = bias[dd + r];
        #pragma unroll
        for (int j = 0; j < 4; ++j) {
            const int oo = o0 + wo * 64 + j * 16 + m16;
            if (oo < OUT_LEN) {
                float* op = out + (size_t)b * COUT * OUT_LEN + (size_t)dd * OUT_LEN + oo;
                #pragma unroll
                for (int r = 0; r < 4; ++r)
                    op[(size_t)r * OUT_LEN] = acc[i][j][r] + bv[r];
            }
        }
    }
#undef ISSUE
#undef SLAB
}

// =====================================================================================
//  OLD PATH (verified @186.9us) — used when ws is too small for P (117 MB)
// =====================================================================================

__global__ __launch_bounds__(256)
void reorder_w1_kernel(const float* __restrict__ w, uint32_t* __restrict__ Wr) {
    const int d   = blockIdx.x;
    const int tid = threadIdx.x;
    __shared__ float wrow[3584];
    const float4* src = (const float4*)(w + (size_t)d * 3584);
    for (int e = tid; e < 896; e += 256) ((float4*)wrow)[e] = src[e];
    __syncthreads();
    const int cc  = tid >> 4;
    const int clp = tid & 15;
    #pragma unroll
    for (int k = 0; k < K_; ++k) {
        const float w0 = wrow[tid * 14 + k];
        const float w1 = wrow[tid * 14 + 7 + k];
        Wr[((size_t)((k * 16 + cc) * 512 + d)) * 16 + clp] = (f2bf(w1) << 16) | f2bf(w0);
    }
}

__global__ __launch_bounds__(256)
void prepack_kernel(const float* __restrict__ x, uint32_t* __restrict__ xpack) {
    const int obx = blockIdx.x;   // 0..31
    const int cc  = blockIdx.y;   // 0..15
    const int b   = blockIdx.z;
    const int tid = threadIdx.x;
    const int o0  = obx * 128;
    __shared__ __align__(16) uint32_t XT[2176];
    const float* xc = x + ((size_t)b * CIN + cc * 32) * L_ + o0;
    #pragma unroll
    for (int r = 0; r < 3; ++r) {
        const int e = r * 256 + tid;
        if (e < 544) {
            const int cp   = e / 34;
            const int col4 = e - cp * 34;
            const int colb = col4 * 4;
            const float* p0 = xc + (size_t)(2 * cp) * L_ + colb;
            const float* p1 = p0 + L_;
            float4 v0, v1;
            if (o0 + colb + 3 < L_) {
                v0 = *(const float4*)p0;
                v1 = *(const float4*)p1;
            } else {
                float a0 = (o0 + colb + 0 < L_) ? p0[0] : 0.f;
                float a1 = (o0 + colb + 1 < L_) ? p0[1] : 0.f;
                float a2 = (o0 + colb + 2 < L_) ? p0[2] : 0.f;
                float a3 = (o0 + colb + 3 < L_) ? p0[3] : 0.f;
                float b0 = (o0 + colb + 0 < L_) ? p1[0] : 0.f;
                float b1 = (o0 + colb + 1 < L_) ? p1[1] : 0.f;
                float b2 = (o0 + colb + 2 < L_) ? p1[2] : 0.f;
                float b3 = (o0 + colb + 3 < L_) ? p1[3] : 0.f;
                v0 = make_float4(a0, a1, a2, a3);
                v1 = make_float4(b0, b1, b2, b3);
            }
            const float* f0 = (const float*)&v0;
            const float* f1 = (const float*)&v1;
            const int cpg = cp >> 1, h = cp & 1;
            #pragma unroll
            for (int ii = 0; ii < 4; ++ii) {
                const int col = colb + ii;
                XT[col * 16 + (((cpg ^ (col & 7)) << 1) | h)] = pack2bf(f0[ii], f1[ii]);
            }
        }
    }
    __syncthreads();
    uint4* dst = (uint4*)xpack + (size_t)((b * 16 + cc) * 32 + obx) * 544;
    const uint4* s4 = (const uint4*)XT;
    #pragma unroll
    for (int r = 0; r < 3; ++r) {
        const int e = r * 256 + tid;
        if (e < 544) dst[e] = s4[e];
    }
}

__global__ __launch_bounds__(256, 2)
void fused_v1_kernel(const float* __restrict__ offs, const ushort_t* __restrict__ Wr,
                     const uint32_t* __restrict__ xpack, const float* __restrict__ bias,
                     float* __restrict__ out) {
    const int bxi  = blockIdx.x;
    const int o0   = bxi * 128;
    const int d0   = blockIdx.y * 128;
    const int b    = blockIdx.z;
    const int tid  = threadIdx.x;
    const int wv   = tid >> 6;
    const int lane = tid & 63;
    const int m16  = lane & 15;
    const int quad = lane >> 4;
    const int ob   = wv * 32;
    const int q2   = quad * 2;

    __shared__ __align__(16) ushort_t As0[4096], As1[4096], As2[4096], As3[4096];
    __shared__ __align__(16) uint32_t XTB0[2304], XTB1[2304];
    __shared__ int    SU[896];
    __shared__ float2 PG[896];

#define ISSUE_A(KK, CC, ASP)                                                      \
    {                                                                             \
        _Pragma("unroll")                                                         \
        for (int r_ = 0; r_ < 2; ++r_) {                                          \
            const int c_ = r_ * 256 + tid;                                        \
            const int row_ = c_ >> 2, pc_ = c_ & 3;                               \
            const ushort_t* g_ = Wr                                               \
                + ((size_t)(((KK) * 16 + (CC)) * 512 + d0 + row_)) * 32 + pc_ * 8;\
            async16(g_, (void*)((ASP) + (r_ * 256 + wv * 64) * 8));               \
        }                                                                         \
    }

#define ISSUE_XTB(CC, XP)                                                         \
    {                                                                             \
        const uint32_t* sp_ = xpack + ((size_t)((b * 16 + (CC)) * 32 + bxi)) * 2176; \
        _Pragma("unroll")                                                         \
        for (int r_ = 0; r_ < 3; ++r_) {                                          \
            const int cb_ = r_ * 256 + wv * 64;                                   \
            if (cb_ < 544) {                                                      \
                const int c_ = r_ * 256 + tid;                                    \
                async16((const void*)(sp_ + (size_t)c_ * 4),                      \
                        (void*)((XP) + (size_t)cb_ * 4));                         \
            }                                                                     \
        }                                                                         \
    }

#define STEP(KK, XP, ASP)                                                         \
    {                                                                             \
        bf16x8 af_[8];                                                            \
        _Pragma("unroll")                                                         \
        for (int i_ = 0; i_ < 8; ++i_)                                            \
            af_[i_] = *(const bf16x8*)&(ASP)[(i_ * 16 + m16) * 32 + quad * 8];    \
        bf16x8 bfr_[2];                                                           \
        _Pragma("unroll")                                                         \
        for (int j_ = 0; j_ < 2; ++j_) {                                          \
            const int row_ = ((KK) << 7) | (ob + j_ * 16 + m16);                  \
            const int u_ = SU[row_];                                              \
            const float2 g_ = PG[row_];                                           \
            const uint32_t* Xr0_ = &(XP)[u_ * 16];                                \
            const uint32_t* Xr1_ = Xr0_ + 16;                                     \
            const int s0_ = u_ & 7, s1_ = (u_ + 1) & 7;                           \
            const uint2 a0_ = *(const uint2*)&Xr0_[((q2     ^ s0_) << 1)];        \
            const uint2 a1_ = *(const uint2*)&Xr0_[(((q2+1) ^ s0_) << 1)];        \
            const uint2 c0_ = *(const uint2*)&Xr1_[((q2     ^ s1_) << 1)];        \
            const uint2 c1_ = *(const uint2*)&Xr1_[(((q2+1) ^ s1_) << 1)];        \
            uint4 rr_;                                                            \
            rr_.x = interp1(a0_.x, c0_.x, g_.x, g_.y);                            \
            rr_.y = interp1(a0_.y, c0_.y, g_.x, g_.y);                            \
            rr_.z = interp1(a1_.x, c1_.x, g_.x, g_.y);                            \
            rr_.w = interp1(a1_.y, c1_.y, g_.x, g_.y);                            \
            __builtin_memcpy(&bfr_[j_], &rr_, 16);                                \
        }                                                                         \
        _Pragma("unroll")                                                         \
        for (int i_ = 0; i_ < 8; ++i_) {                                          \
            _Pragma("unroll")                                                     \
            for (int j_ = 0; j_ < 2; ++j_)                                        \
                acc[i_][j_] = __builtin_amdgcn_mfma_f32_16x16x32_bf16(af_[i_], bfr_[j_], acc[i_][j_], 0, 0, 0); \
        }                                                                         \
    }

#define HALF(CCB, A0_, A1_, A2_, A3_)                                             \
    ISSUE_A(2, (CCB), A2_); ISSUE_A(3, (CCB), A3_); ISSUE_XTB((CCB) + 1, XTB1);   \
    STEP(0, XTB0, A0_); STEP(1, XTB0, A1_); __syncthreads();                      \
    ISSUE_A(4, (CCB), A0_); ISSUE_A(5, (CCB), A1_);                               \
    STEP(2, XTB0, A2_); STEP(3, XTB0, A3_); __syncthreads();                      \
    ISSUE_A(6, (CCB), A2_); ISSUE_A(0, (CCB) + 1, A3_);                           \
    STEP(4, XTB0, A0_); STEP(5, XTB0, A1_); __syncthreads();                      \
    ISSUE_A(1, (CCB) + 1, A0_); ISSUE_A(2, (CCB) + 1, A1_);                       \
    STEP(6, XTB0, A2_); STEP(0, XTB1, A3_); __syncthreads();                      \
    ISSUE_A(3, (CCB) + 1, A2_); ISSUE_A(4, (CCB) + 1, A3_);                       \
    if ((CCB) + 2 < 16) { ISSUE_XTB((CCB) + 2, XTB0); }                           \
    STEP(1, XTB1, A0_); STEP(2, XTB1, A1_); __syncthreads();                      \
    ISSUE_A(5, (CCB) + 1, A0_); ISSUE_A(6, (CCB) + 1, A1_);                       \
    STEP(3, XTB1, A2_); STEP(4, XTB1, A3_); __syncthreads();                      \
    if ((CCB) + 2 < 16) { ISSUE_A(0, (CCB) + 2, A2_); ISSUE_A(1, (CCB) + 2, A3_); } \
    STEP(5, XTB1, A0_); STEP(6, XTB1, A1_); __syncthreads();

    f32x4 acc[8][2];
    #pragma unroll
    for (int i = 0; i < 8; ++i) {
        #pragma unroll
        for (int j = 0; j < 2; ++j) acc[i][j] = (f32x4){0.f, 0.f, 0.f, 0.f};
    }

    ISSUE_XTB(0, XTB0);
    ISSUE_A(0, 0, As0);
    ISSUE_A(1, 0, As1);
    for (int e = tid; e < 896; e += 256) {
        const int k  = e >> 7;
        const int ol = e & 127;
        int o = o0 + ol; if (o > OUT_LEN - 1) o = OUT_LEN - 1;
        const float t0  = (float)o;
        const float off = offs[((size_t)b * OUT_LEN + o) * K_ + k];
        float T = t0 + (float)k + off;
        T = fmaxf(T, t0);
        T = fminf(T, t0 + 6.0f);
        int u0 = (int)floorf(T);
        if (u0 > L_ - 2) u0 = L_ - 2;
        const float g0 = fmaxf(1.0f - fabsf((float)u0 - T), 0.0f);
        const float g1 = fmaxf(1.0f - fabsf((float)(u0 + 1) - T), 0.0f);
        SU[e] = u0 - o0;
        PG[e] = make_float2(g0, g1);
    }
    __syncthreads();

    #pragma unroll 1
    for (int s4 = 0; s4 < 16; s4 += 4) {
        HALF(s4,     As0, As1, As2, As3)
        HALF(s4 + 2, As2, As3, As0, As1)
    }

    #pragma unroll
    for (int i = 0; i < 8; ++i) {
        const int dd = d0 + i * 16 + quad * 4;
        float bv[4];
        #pragma unroll
        for (int r = 0; r < 4; ++r) bv[r] = bias[dd + r];
        #pragma unroll
        for (int j = 0; j < 2; ++j) {
            const int oo = o0 + ob + j * 16 + m16;
            if (oo < OUT_LEN) {
                float* op = out + (size_t)b * COUT * OUT_LEN + (size_t)dd * OUT_LEN + oo;
                #pragma unroll
                for (int r = 0; r < 4; ++r)
                    op[(size_t)r * OUT_LEN] = acc[i][j][r] + bv[r];
            }
        }
    }
#undef ISSUE_A
#undef ISSUE_XTB
#undef STEP
#undef HALF
}

// ---------------- fp32 fallback (round-1 kernel, used only if ws too small) ----------------
#define BM 64
#define BN 64
#define BC 8
#define TT (BC * K_)

__global__ __launch_bounds__(256, 2)
void deform_conv1d_fallback(const float* __restrict__ x, const float* __restrict__ offsets,
                            const float* __restrict__ weight, const float* __restrict__ bias,
                            float* __restrict__ out) {
    const int o0 = blockIdx.x * BN, d0 = blockIdx.y * BM, b = blockIdx.z, tid = threadIdx.x;
    __shared__ int   SU[BN * K_];
    __shared__ float SG0[BN * K_], SG1[BN * K_];
    __shared__ float XT[BC][BN + 8];
    __shared__ float S[BC][K_][BN];
    __shared__ float WT[BM][TT + 1];
    for (int e = tid; e < BN * K_; e += 256) {
        const int ol = e / K_, k = e % K_, o = o0 + ol;
        int u0rel = 0; float g0 = 0.f, g1 = 0.f;
        if (o < OUT_LEN) {
            const float t0 = (float)o;
            const float off = offsets[(size_t)b * OUT_LEN * K_ + (size_t)o * K_ + k];
            float T = fminf(fmaxf(t0 + (float)k + off, t0), t0 + 6.0f);
            int u0 = (int)floorf(T); if (u0 > L_ - 2) u0 = L_ - 2;
            g0 = fmaxf(1.0f - fabsf((float)u0 - T), 0.0f);
            g1 = fmaxf(1.0f - fabsf((float)(u0 + 1) - T), 0.0f);
            u0rel = u0 - o0;
        }
        SU[e] = u0rel; SG0[e] = g0; SG1[e] = g1;
    }
    float acc[4][4];
    #pragma unroll
    for (int i = 0; i < 4; ++i) {
        #pragma unroll
        for (int j = 0; j < 4; ++j) acc[i][j] = 0.f;
    }
    const int ty = tid >> 4, tx = tid & 15;
    const float* xb = x + (size_t)b * CIN * L_;
    for (int c0 = 0; c0 < CIN; c0 += BC) {
        __syncthreads();
        for (int e = tid; e < BC * (BN + 7); e += 256) {
            const int cl = e / (BN + 7), j = e % (BN + 7), pos = o0 + j;
            XT[cl][j] = (pos < L_) ? xb[(size_t)(c0 + cl) * L_ + pos] : 0.f;
        }
        for (int e = tid; e < BM * TT; e += 256) {
            const int d = e / TT, t = e % TT;
            WT[d][t] = weight[(size_t)(d0 + d) * (CIN * K_) + c0 * K_ + t];
        }
        __syncthreads();
        for (int e = tid; e < BC * K_ * BN; e += 256) {
            const int cl = e / (K_ * BN), r = e % (K_ * BN), k = r / BN, ol = r % BN;
            const int p = ol * K_ + k, u = SU[p];
            S[cl][k][ol] = SG0[p] * XT[cl][u] + SG1[p] * XT[cl][u + 1];
        }
        __syncthreads();
        #pragma unroll
        for (int t = 0; t < TT; ++t) {
            const int cl = t / K_, k = t % K_;
            const float4 s4 = *(const float4*)&S[cl][k][tx * 4];
            const float w0 = WT[ty * 4 + 0][t], w1 = WT[ty * 4 + 1][t];
            const float w2 = WT[ty * 4 + 2][t], w3 = WT[ty * 4 + 3][t];
            acc[0][0] += w0 * s4.x; acc[0][1] += w0 * s4.y; acc[0][2] += w0 * s4.z; acc[0][3] += w0 * s4.w;
            acc[1][0] += w1 * s4.x; acc[1][1] += w1 * s4.y; acc[1][2] += w1 * s4.z; acc[1][3] += w1 * s4.w;
            acc[2][0] += w2 * s4.x; acc[2][1] += w2 * s4.y; acc[2][2] += w2 * s4.z; acc[2][3] += w2 * s4.w;
            acc[3][0] += w3 * s4.x; acc[3][1] += w3 * s4.y; acc[3][2] += w3 * s4.z; acc[3][3] += w3 * s4.w;
        }
    }
    #pragma unroll
    for (int i = 0; i < 4; ++i) {
        const int d = d0 + ty * 4 + i;
        const float bvv = bias[d];
        #pragma unroll
        for (int j = 0; j < 4; ++j) {
            const int o = o0 + tx * 4 + j;
            if (o < OUT_LEN)
                out[(size_t)b * COUT * OUT_LEN + (size_t)d * OUT_LEN + o] = acc[i][j] + bvv;
        }
    }
}

extern "C" void kernel_launch(void* const* d_in, const int* in_sizes, int n_in,
                              void* d_out, int out_size, void* d_ws, size_t ws_size,
                              hipStream_t stream) {
    const float* x       = (const float*)d_in[0];
    const float* offsets = (const float*)d_in[1];
    const float* weight  = (const float*)d_in[2];
    const float* bias    = (const float*)d_in[3];
    float* out = (float*)d_out;

    const size_t WR_BYTES = (size_t)512 * 512 * 7 * 2;                  // 3,670,016
    const size_t P_BYTES  = (size_t)4 * 16 * 7 * 32 * 8192;             // 117,440,512
    const size_t XP_BYTES = (size_t)2048 * 544 * 16 + 512;              // 17,826,304

    if (ws_size >= WR_BYTES + P_BYTES) {
        // new path: precomputed interp + 2-phase-sandwich GEMM (128^2, 2 blocks/CU)
        uint32_t* Wr_u32 = (uint32_t*)d_ws;
        ushort_t* Wr     = (ushort_t*)d_ws;
        uint32_t* P      = (uint32_t*)((char*)d_ws + WR_BYTES);
        reorder_w2_kernel<<<512, 256, 0, stream>>>(weight, Wr_u32);
        interp_pack_kernel<<<dim3(32, 16, B_), 256, 0, stream>>>(x, offsets, P);
        gemm_kernel<<<dim3(32, 4, B_), 256, 0, stream>>>(Wr, P, bias, out);
        return;
    }

    if (ws_size >= WR_BYTES + XP_BYTES) {
        // old verified path
        uint32_t* Wr_u32 = (uint32_t*)d_ws;
        ushort_t* Wr     = (ushort_t*)d_ws;
        uint32_t* xpack  = (uint32_t*)((char*)d_ws + WR_BYTES);
        reorder_w1_kernel<<<512, 256, 0, stream>>>(weight, Wr_u32);
        prepack_kernel<<<dim3(32, 16, B_), 256, 0, stream>>>(x, xpack);
        fused_v1_kernel<<<dim3(32, 4, B_), 256, 0, stream>>>(offsets, Wr, xpack, bias, out);
        return;
    }

    dim3 grid((OUT_LEN + BN - 1) / BN, COUT / BM, B_);
    deform_conv1d_fallback<<<grid, 256, 0, stream>>>(x, offsets, weight, bias, out);
}

// Round 13
// 167.077 us; speedup vs baseline: 1.0328x; 1.0109x over previous
//
#include <hip/hip_runtime.h>
#include <hip/hip_bf16.h>
#include <stdint.h>

#define B_      4
#define CIN     512
#define COUT    512
#define L_      4096
#define K_      7
#define OUT_LEN 4090

typedef unsigned short ushort_t;
typedef __attribute__((ext_vector_type(8))) __bf16 bf16x8;
typedef __attribute__((ext_vector_type(4))) float f32x4;

__device__ __forceinline__ uint32_t f2bf(float f) {
    uint32_t u = __float_as_uint(f);
    return (u + 0x7fffu + ((u >> 16) & 1u)) >> 16;
}

__device__ __forceinline__ uint32_t pack2bf(float s0, float s1) {   // s0 -> low 16
    __hip_bfloat162 h = __float22bfloat162_rn(make_float2(s0, s1));
    uint32_t r;
    __builtin_memcpy(&r, &h, 4);
    return r;
}

__device__ __forceinline__ uint32_t interp1(uint32_t wl, uint32_t wh, float g0, float g1) {
    const float l0 = __uint_as_float(wl << 16);
    const float l1 = __uint_as_float(wl & 0xffff0000u);
    const float h0 = __uint_as_float(wh << 16);
    const float h1 = __uint_as_float(wh & 0xffff0000u);
    return pack2bf(g0 * l0 + g1 * h0, g0 * l1 + g1 * h1);
}

__device__ __forceinline__ void async16(const void* g, void* l) {
    __builtin_amdgcn_global_load_lds(
        (const __attribute__((address_space(1))) unsigned int*)g,
        (__attribute__((address_space(3))) unsigned int*)l, 16, 0, 0);
}

// =====================================================================================
//  FINAL (round-11 verified best: gemm 64.7us, MfmaUtil 36%)
//  Layouts (step s = cc*7 + k, s = 0..111):
//   Wr: slab s -> 512 d-rows x 32 bf16, 64 B/row, chunk c at c ^ ((d>>1)&3)
//   P : slab (s, b, obx) -> 128 o-rows x 32 bf16, chunk c at c ^ ((o>>1)&3)
//  gemm: 512 thr / 8 waves (4d x 2o), 256d x 128o tile, 4-slab K=32 rotation,
//  2-phase sandwich per slab {ds_read; stage(s+3); barrier; lgkmcnt(0); setprio;
//  8 MFMA}x2 + slab-end counted vmcnt(6) (2 slabs in flight, never drained).
//  Session 2x2 showed sandwich requires the 8-wave config (anti-composes with
//  2 blocks/CU); this cell is the measured optimum.
// =====================================================================================

// ------- weight reorder+cast, step-linear + chunk-swizzled -------
__global__ __launch_bounds__(256)
void reorder_w2_kernel(const float* __restrict__ w, uint32_t* __restrict__ Wr) {
    const int d   = blockIdx.x;
    const int tid = threadIdx.x;
    __shared__ float wrow[3584];
    const float4* src = (const float4*)(w + (size_t)d * 3584);
    for (int e = tid; e < 896; e += 256) ((float4*)wrow)[e] = src[e];
    __syncthreads();
    const int cc  = tid >> 4;
    const int clp = tid & 15;                                   // pair index in chunk (ch 2clp,2clp+1)
    const int pos = (((clp >> 2) ^ ((d >> 1) & 3)) << 2) | (clp & 3);
    #pragma unroll
    for (int k = 0; k < K_; ++k) {
        const float w0 = wrow[tid * 14 + k];
        const float w1 = wrow[tid * 14 + 7 + k];
        Wr[((size_t)(cc * 7 + k) * 512 + d) * 16 + pos] = (f2bf(w1) << 16) | f2bf(w0);
    }
}

// ------- interp+pack: stage x slab -> LDS, interpolate ONCE, write MFMA-ready P -------
__global__ __launch_bounds__(256)
void interp_pack_kernel(const float* __restrict__ x, const float* __restrict__ offs,
                        uint32_t* __restrict__ P) {
    const int obx = blockIdx.x;   // 0..31
    const int cc  = blockIdx.y;   // 0..15
    const int b   = blockIdx.z;
    const int tid = threadIdx.x;
    const int o0  = obx * 128;
    __shared__ __align__(16) uint32_t XT[2176];   // 136 cols x 16 pair-slots (XOR-swizzled)

    // ---- phase 1: x -> XT (bf16 channel-pairs, per-column XOR on pair-group) ----
    const float* xc = x + ((size_t)b * CIN + cc * 32) * L_ + o0;
    #pragma unroll
    for (int r = 0; r < 3; ++r) {
        const int e = r * 256 + tid;
        if (e < 544) {
            const int cp   = e / 34;
            const int col4 = e - cp * 34;
            const int colb = col4 * 4;
            const float* p0 = xc + (size_t)(2 * cp) * L_ + colb;
            const float* p1 = p0 + L_;
            float4 v0, v1;
            if (o0 + colb + 3 < L_) {
                v0 = *(const float4*)p0;
                v1 = *(const float4*)p1;
            } else {
                float a0 = (o0 + colb + 0 < L_) ? p0[0] : 0.f;
                float a1 = (o0 + colb + 1 < L_) ? p0[1] : 0.f;
                float a2 = (o0 + colb + 2 < L_) ? p0[2] : 0.f;
                float a3 = (o0 + colb + 3 < L_) ? p0[3] : 0.f;
                float b0 = (o0 + colb + 0 < L_) ? p1[0] : 0.f;
                float b1 = (o0 + colb + 1 < L_) ? p1[1] : 0.f;
                float b2 = (o0 + colb + 2 < L_) ? p1[2] : 0.f;
                float b3 = (o0 + colb + 3 < L_) ? p1[3] : 0.f;
                v0 = make_float4(a0, a1, a2, a3);
                v1 = make_float4(b0, b1, b2, b3);
            }
            const float* f0 = (const float*)&v0;
            const float* f1 = (const float*)&v1;
            const int cpg = cp >> 1, hh = cp & 1;
            #pragma unroll
            for (int ii = 0; ii < 4; ++ii) {
                const int col = colb + ii;
                XT[col * 16 + (((cpg ^ (col & 7)) << 1) | hh)] = pack2bf(f0[ii], f1[ii]);
            }
        }
    }
    __syncthreads();

    // ---- phase 2: interpolate, write P slabs (chunk-swizzled for coalesced reads) ----
    const int o_loc = tid >> 1;
    const int h     = tid & 1;                    // channel half: pairs 8h..8h+7
    int o = o0 + o_loc; if (o > OUT_LEN - 1) o = OUT_LEN - 1;
    const float t0f = (float)o;
    const int sr = (o_loc >> 1) & 3;
    uint32_t* Pb = P + ((size_t)((b * 16 + cc) * 7) * 32 + obx) * 2048 + o_loc * 16;
    const int c0 = ((2 * h) ^ sr) << 2;
    const int c1 = ((2 * h + 1) ^ sr) << 2;
    #pragma unroll
    for (int k = 0; k < K_; ++k) {
        const float off = offs[((size_t)b * OUT_LEN + o) * K_ + k];
        float T = t0f + (float)k + off;
        T = fmaxf(T, t0f);
        T = fminf(T, t0f + 6.0f);
        int u0 = (int)floorf(T); if (u0 > L_ - 2) u0 = L_ - 2;
        const float g1 = T - (float)u0;           // == max(0,1-|u0+1-T|)
        const float g0 = 1.0f - g1;               // == max(0,1-|u0-T|)
        const int ul = u0 - o0;
        const uint32_t* R0 = &XT[ul * 16];
        const uint32_t* R1 = &XT[(ul + 1) * 16];
        const int s0 = ul & 7, s1 = (ul + 1) & 7;
        uint32_t ow[8];
        #pragma unroll
        for (int q = 0; q < 4; ++q) {
            const int pg = h * 4 + q;             // pair-group -> pairs 2pg,2pg+1
            const uint2 lo = *(const uint2*)&R0[(pg ^ s0) << 1];
            const uint2 hi = *(const uint2*)&R1[(pg ^ s1) << 1];
            ow[q * 2 + 0] = interp1(lo.x, hi.x, g0, g1);
            ow[q * 2 + 1] = interp1(lo.y, hi.y, g0, g1);
        }
        uint32_t* Pk = Pb + (size_t)k * 65536;    // next k-slab: 32 slabs * 2048 u32
        *(uint4*)&Pk[c0] = make_uint4(ow[0], ow[1], ow[2], ow[3]);
        *(uint4*)&Pk[c1] = make_uint4(ow[4], ow[5], ow[6], ow[7]);
    }
}

// --- GEMM: 256x128 tile, 512 thr / 8 waves of 64x64; 2-phase sandwich per K-32 slab ---
__global__ __launch_bounds__(512, 1)
void gemm_kernel(const ushort_t* __restrict__ Wr, const uint32_t* __restrict__ P,
                 const float* __restrict__ bias, float* __restrict__ out) {
    const int bxi  = blockIdx.x;                  // o-tile (128 wide), 0..31
    const int o0   = bxi * 128;
    const int d0   = blockIdx.y * 256;            // d-tile (256 wide), 0..1
    const int b    = blockIdx.z;
    const int tid  = threadIdx.x;
    const int wv   = tid >> 6;                    // 8 waves
    const int lane = tid & 63;
    const int m16  = lane & 15;
    const int quad = lane >> 4;
    const int wd   = wv >> 1;                     // d-band of wave (64 rows), 0..3
    const int wo   = wv & 1;                      // o-half of wave (64 cols), 0..1
    const int sw   = (m16 >> 1) & 3;              // == (row>>1)&3 for every fragment row
    const int chk  = (quad ^ sw) * 8;             // physical 16B chunk (ushort units)

    // 4-slab rotation: A 4x16KB + B 4x8KB = 96 KB (1 block/CU, 8 waves = 2/SIMD)
    __shared__ __align__(16) ushort_t As0[8192], As1[8192], As2[8192], As3[8192];
    __shared__ __align__(16) ushort_t Bs0[4096], Bs1[4096], Bs2[4096], Bs3[4096];

    const int aoff = (wd * 64 + m16) * 32 + chk;
    const int boff = (wo * 64 + m16) * 32 + chk;

    const ushort_t* Ag = Wr + (size_t)d0 * 32 + (size_t)tid * 8;                      // +s*16384
    const uint32_t* Bg = P + ((size_t)(b * 112) * 32 + bxi) * 2048 + (size_t)tid * 4; // +s*65536

// 3 global_load_lds per thread per slab: 2 x 8KB A-rounds + 1 x 8KB B
#define ISSUE(S, ASP, BSP)                                                    \
    { _Pragma("unroll") for (int r_ = 0; r_ < 2; ++r_)                        \
        async16(Ag + (size_t)(S) * 16384 + r_ * 4096,                         \
                (void*)((ASP) + (r_ * 512 + wv * 64) * 8));                   \
      async16(Bg + (size_t)(S) * 65536,                                       \
              (void*)((BSP) + (size_t)(wv * 64) * 8)); }

// One K-32 slab in the 2-phase sandwich.  Entry invariant: slab's data is
// vmcnt-confirmed and barrier'd.  DOI/SN/ANX/BNX: optional stage of slab SN.
// VN (string): outstanding vmem ops allowed at slab end ("6" = 2 slabs in flight).
#define SLAB(ASP, BSP, DOI, SN, ANX, BNX, VN)                                 \
    {                                                                         \
        bf16x8 af_[4], bA_[2], bB_[2];                                        \
        /* ---- phase 1: read 4 A-frags + 2 B-frags, stage next, MFMA 8 ---- */ \
        _Pragma("unroll")                                                     \
        for (int i_ = 0; i_ < 4; ++i_) af_[i_] = *(const bf16x8*)&(ASP)[aoff + i_ * 512]; \
        bA_[0] = *(const bf16x8*)&(BSP)[boff];                                \
        bA_[1] = *(const bf16x8*)&(BSP)[boff + 512];                          \
        __builtin_amdgcn_sched_barrier(0);                                    \
        if (DOI) { ISSUE(SN, ANX, BNX); }                                     \
        __builtin_amdgcn_s_barrier();                                         \
        asm volatile("s_waitcnt lgkmcnt(0)" ::: "memory");                    \
        __builtin_amdgcn_sched_barrier(0);                                    \
        __builtin_amdgcn_s_setprio(1);                                        \
        _Pragma("unroll")                                                     \
        for (int i_ = 0; i_ < 4; ++i_) {                                      \
            acc[i_][0] = __builtin_amdgcn_mfma_f32_16x16x32_bf16(af_[i_], bA_[0], acc[i_][0], 0, 0, 0); \
            acc[i_][1] = __builtin_amdgcn_mfma_f32_16x16x32_bf16(af_[i_], bA_[1], acc[i_][1], 0, 0, 0); \
        }                                                                     \
        __builtin_amdgcn_s_setprio(0);                                        \
        /* ---- phase 2: read remaining 2 B-frags, MFMA 8 ---- */             \
        bB_[0] = *(const bf16x8*)&(BSP)[boff + 1024];                         \
        bB_[1] = *(const bf16x8*)&(BSP)[boff + 1536];                         \
        __builtin_amdgcn_sched_barrier(0);                                    \
        __builtin_amdgcn_s_barrier();                                         \
        asm volatile("s_waitcnt lgkmcnt(0)" ::: "memory");                    \
        __builtin_amdgcn_sched_barrier(0);                                    \
        __builtin_amdgcn_s_setprio(1);                                        \
        _Pragma("unroll")                                                     \
        for (int i_ = 0; i_ < 4; ++i_) {                                      \
            acc[i_][2] = __builtin_amdgcn_mfma_f32_16x16x32_bf16(af_[i_], bB_[0], acc[i_][2], 0, 0, 0); \
            acc[i_][3] = __builtin_amdgcn_mfma_f32_16x16x32_bf16(af_[i_], bB_[1], acc[i_][3], 0, 0, 0); \
        }                                                                     \
        __builtin_amdgcn_s_setprio(0);                                        \
        /* ---- slab end: confirm next slab (counted, never 0 mid-loop) ---- */ \
        asm volatile("s_waitcnt vmcnt(" VN ")" ::: "memory");                 \
        __builtin_amdgcn_s_barrier();                                         \
        __builtin_amdgcn_sched_barrier(0);                                    \
    }

    f32x4 acc[4][4];
    #pragma unroll
    for (int i = 0; i < 4; ++i) {
        #pragma unroll
        for (int j = 0; j < 4; ++j) acc[i][j] = (f32x4){0.f, 0.f, 0.f, 0.f};
    }

    // prologue: slabs 0,1,2 in flight (9 ops/thread); confirm slab 0 (6 left)
    ISSUE(0, As0, Bs0);
    ISSUE(1, As1, Bs1);
    ISSUE(2, As2, Bs2);
    asm volatile("s_waitcnt vmcnt(6)" ::: "memory");
    __builtin_amdgcn_s_barrier();
    __builtin_amdgcn_sched_barrier(0);

    // steady state: slab s issues stage(s+3) (distance 3, 2 slabs always in flight).
    // WAR: stage(s+3) targets buf[(s-1)&3]; its reads retired at slab s-1's
    // lgkmcnt(0) and are block-wide ordered by the end-of-slab barrier.
    #pragma unroll 1
    for (int t = 0; t < 108; t += 4) {
        SLAB(As0, Bs0, 1, t + 3, As3, Bs3, "6")
        SLAB(As1, Bs1, 1, t + 4, As0, Bs0, "6")
        SLAB(As2, Bs2, 1, t + 5, As1, Bs1, "6")
        SLAB(As3, Bs3, 1, t + 6, As2, Bs2, "6")
    }
    // peel: slabs 108..111 (loop issued through 110; 108 issues 111)
    SLAB(As0, Bs0, 1, 111, As3, Bs3, "6")     // slab 108 -> confirm 109
    SLAB(As1, Bs1, 0, 0, As0, Bs0, "3")       // slab 109 -> confirm 110
    SLAB(As2, Bs2, 0, 0, As0, Bs0, "0")       // slab 110 -> confirm 111
    SLAB(As3, Bs3, 0, 0, As0, Bs0, "0")       // slab 111

    // epilogue (verified C/D layout: col=o (m16), row=quad*4+r on the d dim)
    #pragma unroll
    for (int i = 0; i < 4; ++i) {
        const int dd = d0 + wd * 64 + i * 16 + quad * 4;
        float bv[4];
        #pragma unroll
        for (int r = 0; r < 4; ++r) bv[r] = bias[dd + r];
        #pragma unroll
        for (int j = 0; j < 4; ++j) {
            const int oo = o0 + wo * 64 + j * 16 + m16;
            if (oo < OUT_LEN) {
                float* op = out + (size_t)b * COUT * OUT_LEN + (size_t)dd * OUT_LEN + oo;
                #pragma unroll
                for (int r = 0; r < 4; ++r)
                    op[(size_t)r * OUT_LEN] = acc[i][j][r] + bv[r];
            }
        }
    }
#undef ISSUE
#undef SLAB
}

// =====================================================================================
//  OLD PATH (verified @186.9us) — used when ws is too small for P (117 MB)
// =====================================================================================

__global__ __launch_bounds__(256)
void reorder_w1_kernel(const float* __restrict__ w, uint32_t* __restrict__ Wr) {
    const int d   = blockIdx.x;
    const int tid = threadIdx.x;
    __shared__ float wrow[3584];
    const float4* src = (const float4*)(w + (size_t)d * 3584);
    for (int e = tid; e < 896; e += 256) ((float4*)wrow)[e] = src[e];
    __syncthreads();
    const int cc  = tid >> 4;
    const int clp = tid & 15;
    #pragma unroll
    for (int k = 0; k < K_; ++k) {
        const float w0 = wrow[tid * 14 + k];
        const float w1 = wrow[tid * 14 + 7 + k];
        Wr[((size_t)((k * 16 + cc) * 512 + d)) * 16 + clp] = (f2bf(w1) << 16) | f2bf(w0);
    }
}

__global__ __launch_bounds__(256)
void prepack_kernel(const float* __restrict__ x, uint32_t* __restrict__ xpack) {
    const int obx = blockIdx.x;   // 0..31
    const int cc  = blockIdx.y;   // 0..15
    const int b   = blockIdx.z;
    const int tid = threadIdx.x;
    const int o0  = obx * 128;
    __shared__ __align__(16) uint32_t XT[2176];
    const float* xc = x + ((size_t)b * CIN + cc * 32) * L_ + o0;
    #pragma unroll
    for (int r = 0; r < 3; ++r) {
        const int e = r * 256 + tid;
        if (e < 544) {
            const int cp   = e / 34;
            const int col4 = e - cp * 34;
            const int colb = col4 * 4;
            const float* p0 = xc + (size_t)(2 * cp) * L_ + colb;
            const float* p1 = p0 + L_;
            float4 v0, v1;
            if (o0 + colb + 3 < L_) {
                v0 = *(const float4*)p0;
                v1 = *(const float4*)p1;
            } else {
                float a0 = (o0 + colb + 0 < L_) ? p0[0] : 0.f;
                float a1 = (o0 + colb + 1 < L_) ? p0[1] : 0.f;
                float a2 = (o0 + colb + 2 < L_) ? p0[2] : 0.f;
                float a3 = (o0 + colb + 3 < L_) ? p0[3] : 0.f;
                float b0 = (o0 + colb + 0 < L_) ? p1[0] : 0.f;
                float b1 = (o0 + colb + 1 < L_) ? p1[1] : 0.f;
                float b2 = (o0 + colb + 2 < L_) ? p1[2] : 0.f;
                float b3 = (o0 + colb + 3 < L_) ? p1[3] : 0.f;
                v0 = make_float4(a0, a1, a2, a3);
                v1 = make_float4(b0, b1, b2, b3);
            }
            const float* f0 = (const float*)&v0;
            const float* f1 = (const float*)&v1;
            const int cpg = cp >> 1, h = cp & 1;
            #pragma unroll
            for (int ii = 0; ii < 4; ++ii) {
                const int col = colb + ii;
                XT[col * 16 + (((cpg ^ (col & 7)) << 1) | h)] = pack2bf(f0[ii], f1[ii]);
            }
        }
    }
    __syncthreads();
    uint4* dst = (uint4*)xpack + (size_t)((b * 16 + cc) * 32 + obx) * 544;
    const uint4* s4 = (const uint4*)XT;
    #pragma unroll
    for (int r = 0; r < 3; ++r) {
        const int e = r * 256 + tid;
        if (e < 544) dst[e] = s4[e];
    }
}

__global__ __launch_bounds__(256, 2)
void fused_v1_kernel(const float* __restrict__ offs, const ushort_t* __restrict__ Wr,
                     const uint32_t* __restrict__ xpack, const float* __restrict__ bias,
                     float* __restrict__ out) {
    const int bxi  = blockIdx.x;
    const int o0   = bxi * 128;
    const int d0   = blockIdx.y * 128;
    const int b    = blockIdx.z;
    const int tid  = threadIdx.x;
    const int wv   = tid >> 6;
    const int lane = tid & 63;
    const int m16  = lane & 15;
    const int quad = lane >> 4;
    const int ob   = wv * 32;
    const int q2   = quad * 2;

    __shared__ __align__(16) ushort_t As0[4096], As1[4096], As2[4096], As3[4096];
    __shared__ __align__(16) uint32_t XTB0[2304], XTB1[2304];
    __shared__ int    SU[896];
    __shared__ float2 PG[896];

#define ISSUE_A(KK, CC, ASP)                                                      \
    {                                                                             \
        _Pragma("unroll")                                                         \
        for (int r_ = 0; r_ < 2; ++r_) {                                          \
            const int c_ = r_ * 256 + tid;                                        \
            const int row_ = c_ >> 2, pc_ = c_ & 3;                               \
            const ushort_t* g_ = Wr                                               \
                + ((size_t)(((KK) * 16 + (CC)) * 512 + d0 + row_)) * 32 + pc_ * 8;\
            async16(g_, (void*)((ASP) + (r_ * 256 + wv * 64) * 8));               \
        }                                                                         \
    }

#define ISSUE_XTB(CC, XP)                                                         \
    {                                                                             \
        const uint32_t* sp_ = xpack + ((size_t)((b * 16 + (CC)) * 32 + bxi)) * 2176; \
        _Pragma("unroll")                                                         \
        for (int r_ = 0; r_ < 3; ++r_) {                                          \
            const int cb_ = r_ * 256 + wv * 64;                                   \
            if (cb_ < 544) {                                                      \
                const int c_ = r_ * 256 + tid;                                    \
                async16((const void*)(sp_ + (size_t)c_ * 4),                      \
                        (void*)((XP) + (size_t)cb_ * 4));                         \
            }                                                                     \
        }                                                                         \
    }

#define STEP(KK, XP, ASP)                                                         \
    {                                                                             \
        bf16x8 af_[8];                                                            \
        _Pragma("unroll")                                                         \
        for (int i_ = 0; i_ < 8; ++i_)                                            \
            af_[i_] = *(const bf16x8*)&(ASP)[(i_ * 16 + m16) * 32 + quad * 8];    \
        bf16x8 bfr_[2];                                                           \
        _Pragma("unroll")                                                         \
        for (int j_ = 0; j_ < 2; ++j_) {                                          \
            const int row_ = ((KK) << 7) | (ob + j_ * 16 + m16);                  \
            const int u_ = SU[row_];                                              \
            const float2 g_ = PG[row_];                                           \
            const uint32_t* Xr0_ = &(XP)[u_ * 16];                                \
            const uint32_t* Xr1_ = Xr0_ + 16;                                     \
            const int s0_ = u_ & 7, s1_ = (u_ + 1) & 7;                           \
            const uint2 a0_ = *(const uint2*)&Xr0_[((q2     ^ s0_) << 1)];        \
            const uint2 a1_ = *(const uint2*)&Xr0_[(((q2+1) ^ s0_) << 1)];        \
            const uint2 c0_ = *(const uint2*)&Xr1_[((q2     ^ s1_) << 1)];        \
            const uint2 c1_ = *(const uint2*)&Xr1_[(((q2+1) ^ s1_) << 1)];        \
            uint4 rr_;                                                            \
            rr_.x = interp1(a0_.x, c0_.x, g_.x, g_.y);                            \
            rr_.y = interp1(a0_.y, c0_.y, g_.x, g_.y);                            \
            rr_.z = interp1(a1_.x, c1_.x, g_.x, g_.y);                            \
            rr_.w = interp1(a1_.y, c1_.y, g_.x, g_.y);                            \
            __builtin_memcpy(&bfr_[j_], &rr_, 16);                                \
        }                                                                         \
        _Pragma("unroll")                                                         \
        for (int i_ = 0; i_ < 8; ++i_) {                                          \
            _Pragma("unroll")                                                     \
            for (int j_ = 0; j_ < 2; ++j_)                                        \
                acc[i_][j_] = __builtin_amdgcn_mfma_f32_16x16x32_bf16(af_[i_], bfr_[j_], acc[i_][j_], 0, 0, 0); \
        }                                                                         \
    }

#define HALF(CCB, A0_, A1_, A2_, A3_)                                             \
    ISSUE_A(2, (CCB), A2_); ISSUE_A(3, (CCB), A3_); ISSUE_XTB((CCB) + 1, XTB1);   \
    STEP(0, XTB0, A0_); STEP(1, XTB0, A1_); __syncthreads();                      \
    ISSUE_A(4, (CCB), A0_); ISSUE_A(5, (CCB), A1_);                               \
    STEP(2, XTB0, A2_); STEP(3, XTB0, A3_); __syncthreads();                      \
    ISSUE_A(6, (CCB), A2_); ISSUE_A(0, (CCB) + 1, A3_);                           \
    STEP(4, XTB0, A0_); STEP(5, XTB0, A1_); __syncthreads();                      \
    ISSUE_A(1, (CCB) + 1, A0_); ISSUE_A(2, (CCB) + 1, A1_);                       \
    STEP(6, XTB0, A2_); STEP(0, XTB1, A3_); __syncthreads();                      \
    ISSUE_A(3, (CCB) + 1, A2_); ISSUE_A(4, (CCB) + 1, A3_);                       \
    if ((CCB) + 2 < 16) { ISSUE_XTB((CCB) + 2, XTB0); }                           \
    STEP(1, XTB1, A0_); STEP(2, XTB1, A1_); __syncthreads();                      \
    ISSUE_A(5, (CCB) + 1, A0_); ISSUE_A(6, (CCB) + 1, A1_);                       \
    STEP(3, XTB1, A2_); STEP(4, XTB1, A3_); __syncthreads();                      \
    if ((CCB) + 2 < 16) { ISSUE_A(0, (CCB) + 2, A2_); ISSUE_A(1, (CCB) + 2, A3_); } \
    STEP(5, XTB1, A0_); STEP(6, XTB1, A1_); __syncthreads();

    f32x4 acc[8][2];
    #pragma unroll
    for (int i = 0; i < 8; ++i) {
        #pragma unroll
        for (int j = 0; j < 2; ++j) acc[i][j] = (f32x4){0.f, 0.f, 0.f, 0.f};
    }

    ISSUE_XTB(0, XTB0);
    ISSUE_A(0, 0, As0);
    ISSUE_A(1, 0, As1);
    for (int e = tid; e < 896; e += 256) {
        const int k  = e >> 7;
        const int ol = e & 127;
        int o = o0 + ol; if (o > OUT_LEN - 1) o = OUT_LEN - 1;
        const float t0  = (float)o;
        const float off = offs[((size_t)b * OUT_LEN + o) * K_ + k];
        float T = t0 + (float)k + off;
        T = fmaxf(T, t0);
        T = fminf(T, t0 + 6.0f);
        int u0 = (int)floorf(T);
        if (u0 > L_ - 2) u0 = L_ - 2;
        const float g0 = fmaxf(1.0f - fabsf((float)u0 - T), 0.0f);
        const float g1 = fmaxf(1.0f - fabsf((float)(u0 + 1) - T), 0.0f);
        SU[e] = u0 - o0;
        PG[e] = make_float2(g0, g1);
    }
    __syncthreads();

    #pragma unroll 1
    for (int s4 = 0; s4 < 16; s4 += 4) {
        HALF(s4,     As0, As1, As2, As3)
        HALF(s4 + 2, As2, As3, As0, As1)
    }

    #pragma unroll
    for (int i = 0; i < 8; ++i) {
        const int dd = d0 + i * 16 + quad * 4;
        float bv[4];
        #pragma unroll
        for (int r = 0; r < 4; ++r) bv[r] = bias[dd + r];
        #pragma unroll
        for (int j = 0; j < 2; ++j) {
            const int oo = o0 + ob + j * 16 + m16;
            if (oo < OUT_LEN) {
                float* op = out + (size_t)b * COUT * OUT_LEN + (size_t)dd * OUT_LEN + oo;
                #pragma unroll
                for (int r = 0; r < 4; ++r)
                    op[(size_t)r * OUT_LEN] = acc[i][j][r] + bv[r];
            }
        }
    }
#undef ISSUE_A
#undef ISSUE_XTB
#undef STEP
#undef HALF
}

// ---------------- fp32 fallback (round-1 kernel, used only if ws too small) ----------------
#define BM 64
#define BN 64
#define BC 8
#define TT (BC * K_)

__global__ __launch_bounds__(256, 2)
void deform_conv1d_fallback(const float* __restrict__ x, const float* __restrict__ offsets,
                            const float* __restrict__ weight, const float* __restrict__ bias,
                            float* __restrict__ out) {
    const int o0 = blockIdx.x * BN, d0 = blockIdx.y * BM, b = blockIdx.z, tid = threadIdx.x;
    __shared__ int   SU[BN * K_];
    __shared__ float SG0[BN * K_], SG1[BN * K_];
    __shared__ float XT[BC][BN + 8];
    __shared__ float S[BC][K_][BN];
    __shared__ float WT[BM][TT + 1];
    for (int e = tid; e < BN * K_; e += 256) {
        const int ol = e / K_, k = e % K_, o = o0 + ol;
        int u0rel = 0; float g0 = 0.f, g1 = 0.f;
        if (o < OUT_LEN) {
            const float t0 = (float)o;
            const float off = offsets[(size_t)b * OUT_LEN * K_ + (size_t)o * K_ + k];
            float T = fminf(fmaxf(t0 + (float)k + off, t0), t0 + 6.0f);
            int u0 = (int)floorf(T); if (u0 > L_ - 2) u0 = L_ - 2;
            g0 = fmaxf(1.0f - fabsf((float)u0 - T), 0.0f);
            g1 = fmaxf(1.0f - fabsf((float)(u0 + 1) - T), 0.0f);
            u0rel = u0 - o0;
        }
        SU[e] = u0rel; SG0[e] = g0; SG1[e] = g1;
    }
    float acc[4][4];
    #pragma unroll
    for (int i = 0; i < 4; ++i) {
        #pragma unroll
        for (int j = 0; j < 4; ++j) acc[i][j] = 0.f;
    }
    const int ty = tid >> 4, tx = tid & 15;
    const float* xb = x + (size_t)b * CIN * L_;
    for (int c0 = 0; c0 < CIN; c0 += BC) {
        __syncthreads();
        for (int e = tid; e < BC * (BN + 7); e += 256) {
            const int cl = e / (BN + 7), j = e % (BN + 7), pos = o0 + j;
            XT[cl][j] = (pos < L_) ? xb[(size_t)(c0 + cl) * L_ + pos] : 0.f;
        }
        for (int e = tid; e < BM * TT; e += 256) {
            const int d = e / TT, t = e % TT;
            WT[d][t] = weight[(size_t)(d0 + d) * (CIN * K_) + c0 * K_ + t];
        }
        __syncthreads();
        for (int e = tid; e < BC * K_ * BN; e += 256) {
            const int cl = e / (K_ * BN), r = e % (K_ * BN), k = r / BN, ol = r % BN;
            const int p = ol * K_ + k, u = SU[p];
            S[cl][k][ol] = SG0[p] * XT[cl][u] + SG1[p] * XT[cl][u + 1];
        }
        __syncthreads();
        #pragma unroll
        for (int t = 0; t < TT; ++t) {
            const int cl = t / K_, k = t % K_;
            const float4 s4 = *(const float4*)&S[cl][k][tx * 4];
            const float w0 = WT[ty * 4 + 0][t], w1 = WT[ty * 4 + 1][t];
            const float w2 = WT[ty * 4 + 2][t], w3 = WT[ty * 4 + 3][t];
            acc[0][0] += w0 * s4.x; acc[0][1] += w0 * s4.y; acc[0][2] += w0 * s4.z; acc[0][3] += w0 * s4.w;
            acc[1][0] += w1 * s4.x; acc[1][1] += w1 * s4.y; acc[1][2] += w1 * s4.z; acc[1][3] += w1 * s4.w;
            acc[2][0] += w2 * s4.x; acc[2][1] += w2 * s4.y; acc[2][2] += w2 * s4.z; acc[2][3] += w2 * s4.w;
            acc[3][0] += w3 * s4.x; acc[3][1] += w3 * s4.y; acc[3][2] += w3 * s4.z; acc[3][3] += w3 * s4.w;
        }
    }
    #pragma unroll
    for (int i = 0; i < 4; ++i) {
        const int d = d0 + ty * 4 + i;
        const float bvv = bias[d];
        #pragma unroll
        for (int j = 0; j < 4; ++j) {
            const int o = o0 + tx * 4 + j;
            if (o < OUT_LEN)
                out[(size_t)b * COUT * OUT_LEN + (size_t)d * OUT_LEN + o] = acc[i][j] + bvv;
        }
    }
}

extern "C" void kernel_launch(void* const* d_in, const int* in_sizes, int n_in,
                              void* d_out, int out_size, void* d_ws, size_t ws_size,
                              hipStream_t stream) {
    const float* x       = (const float*)d_in[0];
    const float* offsets = (const float*)d_in[1];
    const float* weight  = (const float*)d_in[2];
    const float* bias    = (const float*)d_in[3];
    float* out = (float*)d_out;

    const size_t WR_BYTES = (size_t)512 * 512 * 7 * 2;                  // 3,670,016
    const size_t P_BYTES  = (size_t)4 * 16 * 7 * 32 * 8192;             // 117,440,512
    const size_t XP_BYTES = (size_t)2048 * 544 * 16 + 512;              // 17,826,304

    if (ws_size >= WR_BYTES + P_BYTES) {
        // final path: precomputed interp + 8-wave 2-phase-sandwich counted-vmcnt GEMM
        uint32_t* Wr_u32 = (uint32_t*)d_ws;
        ushort_t* Wr     = (ushort_t*)d_ws;
        uint32_t* P      = (uint32_t*)((char*)d_ws + WR_BYTES);
        reorder_w2_kernel<<<512, 256, 0, stream>>>(weight, Wr_u32);
        interp_pack_kernel<<<dim3(32, 16, B_), 256, 0, stream>>>(x, offsets, P);
        gemm_kernel<<<dim3(32, 2, B_), 512, 0, stream>>>(Wr, P, bias, out);
        return;
    }

    if (ws_size >= WR_BYTES + XP_BYTES) {
        // old verified path
        uint32_t* Wr_u32 = (uint32_t*)d_ws;
        ushort_t* Wr     = (ushort_t*)d_ws;
        uint32_t* xpack  = (uint32_t*)((char*)d_ws + WR_BYTES);
        reorder_w1_kernel<<<512, 256, 0, stream>>>(weight, Wr_u32);
        prepack_kernel<<<dim3(32, 16, B_), 256, 0, stream>>>(x, xpack);
        fused_v1_kernel<<<dim3(32, 4, B_), 256, 0, stream>>>(offsets, Wr, xpack, bias, out);
        return;
    }

    dim3 grid((OUT_LEN + BN - 1) / BN, COUT / BM, B_);
    deform_conv1d_fallback<<<grid, 256, 0, stream>>>(x, offsets, weight, bias, out);
}